// Round 2
// baseline (403.165 us; speedup 1.0000x reference)
//
#include <hip/hip_runtime.h>
#include <stdint.h>

#define DIMC 1024
#define HEADS 16
#define HD 64
#define HIDDENC 4096
#define BATCH 2
#define SEQ 2048
#define MTOK (BATCH*SEQ)
#define NSLOT 80            // split-K chunk slots per (b,h): 8*1+8*2+8*3+8*4
#define BH_ELEMS (NSLOT*64*64)   // bf16 elems of O_part per bh = 327680

typedef __bf16 bf16x8 __attribute__((ext_vector_type(8)));
typedef float f32x4 __attribute__((ext_vector_type(4)));

__device__ __forceinline__ float bf2f(unsigned short u) {
    union { unsigned int u; float f; } v; v.u = ((unsigned int)u) << 16; return v.f;
}
__device__ __forceinline__ unsigned short f2bf(float f) {
    union { float f; unsigned int u; } v; v.f = f;
    unsigned int r = v.u + 0x7fffu + ((v.u >> 16) & 1u);
    return (unsigned short)(r >> 16);
}
// pack 2 f32 -> 2 bf16 (RNE), src0 -> low half (T12 recipe, guide-verified)
__device__ __forceinline__ unsigned int cvt_pk_bf16(float lo, float hi) {
    unsigned int r;
    asm("v_cvt_pk_bf16_f32 %0, %1, %2" : "=v"(r) : "v"(lo), "v"(hi));
    return r;
}
// 2^x (log2e is pre-folded into the Q scale)
__device__ __forceinline__ float exp2_fast(float x) {
#if __has_builtin(__builtin_amdgcn_exp2f)
    return __builtin_amdgcn_exp2f(x);
#else
    float r;
    asm("v_exp_f32 %0, %1" : "=v"(r) : "v"(x));
    return r;
#endif
}

#define GLOAD_LDS(g, l) \
    __builtin_amdgcn_global_load_lds( \
        (const __attribute__((address_space(1))) void*)(g), \
        (__attribute__((address_space(3))) void*)(l), 16, 0, 0)

// O_part is split across d_out (first 25 bh) and the x1 region (last 7 bh).
__device__ __forceinline__ unsigned short* opart_base(
    unsigned short* o0, unsigned short* o1, int bh) {
    return (bh < 25) ? (o0 + (size_t)bh * BH_ELEMS)
                     : (o1 + (size_t)(bh - 25) * BH_ELEMS);
}

// ---------------------------------------------------------------------------
// Fused weight transposes: fp32 (K x N) -> bf16 (N x K) for all 4 weights.
// ---------------------------------------------------------------------------
__device__ __forceinline__ void tp_tile(const float* __restrict__ in,
                                        unsigned short* __restrict__ out,
                                        int K, int N, int tn, int tk, int tid,
                                        unsigned short (*tile)[65]) {
    for (int c = tid; c < 1024; c += 256) {
        int r = c >> 4, coff = (c & 15) * 4;
        float4 v = *(const float4*)(in + (size_t)(tk + r) * N + tn + coff);
        tile[r][coff + 0] = f2bf(v.x);
        tile[r][coff + 1] = f2bf(v.y);
        tile[r][coff + 2] = f2bf(v.z);
        tile[r][coff + 3] = f2bf(v.w);
    }
    __syncthreads();
    for (int c = tid; c < 512; c += 256) {
        int rn = c >> 3, off = (c & 7) * 8;
        unsigned short tmp[8];
        #pragma unroll
        for (int j = 0; j < 8; j++) tmp[j] = tile[off + j][rn];
        *(uint4*)(out + (size_t)(tn + rn) * K + tk + off) = *(uint4*)tmp;
    }
}

__global__ __launch_bounds__(256) void fused_transpose(
    const float* __restrict__ qkvw, const float* __restrict__ projw,
    const float* __restrict__ fc1w, const float* __restrict__ fc2w,
    unsigned short* __restrict__ qkv_wT, unsigned short* __restrict__ proj_wT,
    unsigned short* __restrict__ fc1_wT, unsigned short* __restrict__ fc2_wT) {
    __shared__ unsigned short tile[64][65];
    int id = blockIdx.x, tid = threadIdx.x;
    if (id < 768) {
        tp_tile(qkvw, qkv_wT, 1024, 3072, (id % 48) * 64, (id / 48) * 64, tid, tile);
    } else if (id < 1024) {
        id -= 768;
        tp_tile(projw, proj_wT, 1024, 1024, (id % 16) * 64, (id / 16) * 64, tid, tile);
    } else if (id < 2048) {
        id -= 1024;
        tp_tile(fc1w, fc1_wT, 1024, 4096, (id % 64) * 64, (id / 64) * 64, tid, tile);
    } else {
        id -= 2048;
        tp_tile(fc2w, fc2_wT, 4096, 1024, (id % 16) * 64, (id / 16) * 64, tid, tile);
    }
}

// ---------------------------------------------------------------------------
// Per-head V transpose: v_buf (bh, t, d) -> vT_buf (bh, d, t), bf16.
// ---------------------------------------------------------------------------
__global__ __launch_bounds__(256) void transpose_v(const unsigned short* __restrict__ in,
                                                   unsigned short* __restrict__ out) {
    __shared__ unsigned short tile[64][65];
    int t0 = blockIdx.x * 64;
    int bh = blockIdx.y;
    const unsigned short* ip = in + (size_t)bh * SEQ * HD;
    unsigned short* op = out + (size_t)bh * HD * SEQ;
    int tid = threadIdx.x;
    for (int c = tid; c < 512; c += 256) {
        int r = c >> 3, off = (c & 7) * 8;
        *(uint4*)&tile[r][off] = *(const uint4*)(ip + (size_t)(t0 + r) * HD + off);
    }
    __syncthreads();
    for (int c = tid; c < 512; c += 256) {
        int rn = c >> 3, off = (c & 7) * 8;
        unsigned short tmp[8];
        #pragma unroll
        for (int j = 0; j < 8; j++) tmp[j] = tile[off + j][rn];
        *(uint4*)(op + (size_t)rn * SEQ + t0 + off) = *(uint4*)tmp;
    }
}

// ---------------------------------------------------------------------------
// LayerNorm: f32 input, f32 w/b, bf16 output. One block per row (DIMC=1024).
// ---------------------------------------------------------------------------
__global__ __launch_bounds__(256) void ln_kernel(const float* __restrict__ inp,
                                                 const float* __restrict__ w,
                                                 const float* __restrict__ b,
                                                 unsigned short* __restrict__ out) {
    int row = blockIdx.x;
    int tid = threadIdx.x;
    int base = tid * 4;
    float4 v = *(const float4*)(inp + (size_t)row * DIMC + base);
    float x[4] = {v.x, v.y, v.z, v.w};
    float s1 = x[0] + x[1] + x[2] + x[3];
    float s2 = x[0]*x[0] + x[1]*x[1] + x[2]*x[2] + x[3]*x[3];
    #pragma unroll
    for (int off = 32; off > 0; off >>= 1) {
        s1 += __shfl_xor(s1, off);
        s2 += __shfl_xor(s2, off);
    }
    __shared__ float red[8];
    int wv = tid >> 6;
    if ((tid & 63) == 0) { red[wv] = s1; red[4 + wv] = s2; }
    __syncthreads();
    s1 = red[0] + red[1] + red[2] + red[3];
    s2 = red[4] + red[5] + red[6] + red[7];
    float mean = s1 * (1.0f / DIMC);
    float var  = s2 * (1.0f / DIMC) - mean * mean;
    float rstd = rsqrtf(var + 1e-5f);
    float4 wv4 = *(const float4*)(w + base);
    float4 bv4 = *(const float4*)(b + base);
    ushort4 o;
    o.x = f2bf((x[0] - mean) * rstd * wv4.x + bv4.x);
    o.y = f2bf((x[1] - mean) * rstd * wv4.y + bv4.y);
    o.z = f2bf((x[2] - mean) * rstd * wv4.z + bv4.z);
    o.w = f2bf((x[3] - mean) * rstd * wv4.w + bv4.w);
    *(ushort4*)(out + (size_t)row * DIMC + base) = o;
}

// ---------------------------------------------------------------------------
// bf16 MFMA GEMM: C(M x N) = A(M x K) @ BT(N x K)^T.
// Tile TM x 128, BK-deep staging via global_load_lds, 4 waves (2x2).
// XOR-swizzled LDS layout -> conflict-free ds_read_b128.
// ---------------------------------------------------------------------------
enum { EP_QKV = 0, EP_PROJ = 1, EP_FC1 = 2, EP_FC2 = 3 };

template <int MODE, int N, int K, int TM, int BK>
__global__ __launch_bounds__(256) void gemm_kernel(
    const unsigned short* __restrict__ A,
    const unsigned short* __restrict__ BT,
    const float* __restrict__ bias,
    const float* __restrict__ res,      // fp32 residual (PROJ: x, FC2: x1)
    void* __restrict__ out0,
    unsigned short* __restrict__ q_buf,
    unsigned short* __restrict__ k_buf,
    unsigned short* __restrict__ v_buf) {
    constexpr int MI = TM / 32;
    constexpr int CPR = BK / 8;
    __shared__ __align__(16) unsigned short As[TM * BK];
    __shared__ __align__(16) unsigned short Bs[128 * BK];
    const int tid = threadIdx.x;
    const int m0 = blockIdx.y * TM;
    const int n0 = blockIdx.x * 128;
    const int wave = tid >> 6, lane = tid & 63;
    const int wm = wave >> 1, wn = wave & 1;
    const int quad = lane >> 4, l16 = lane & 15;
    const int swz = l16 & (CPR - 1);

    f32x4 acc[MI][4] = {};

    for (int kk = 0; kk < K; kk += BK) {
        __syncthreads();
        #pragma unroll
        for (int it = 0; it < TM * BK / 2048; ++it) {
            int c = tid + 256 * it;
            int row = c / CPR, jj = c % CPR;
            int col8 = (jj ^ (row & (CPR - 1))) * 8;
            GLOAD_LDS(A + (size_t)(m0 + row) * K + kk + col8, As + (size_t)c * 8);
        }
        #pragma unroll
        for (int it = 0; it < 128 * BK / 2048; ++it) {
            int c = tid + 256 * it;
            int row = c / CPR, jj = c % CPR;
            int col8 = (jj ^ (row & (CPR - 1))) * 8;
            GLOAD_LDS(BT + (size_t)(n0 + row) * K + kk + col8, Bs + (size_t)c * 8);
        }
        __syncthreads();
        #pragma unroll
        for (int kk2 = 0; kk2 < BK / 32; ++kk2) {
            bf16x8 af[MI], bfv[4];
            #pragma unroll
            for (int i = 0; i < MI; i++) {
                int row = 16 * MI * wm + 16 * i + l16;
                int sj = (4 * kk2 + quad) ^ swz;
                af[i] = *(const bf16x8*)&As[row * BK + sj * 8];
            }
            #pragma unroll
            for (int j = 0; j < 4; j++) {
                int row = 64 * wn + 16 * j + l16;
                int sj = (4 * kk2 + quad) ^ swz;
                bfv[j] = *(const bf16x8*)&Bs[row * BK + sj * 8];
            }
            #pragma unroll
            for (int i = 0; i < MI; i++)
                #pragma unroll
                for (int j = 0; j < 4; j++)
                    acc[i][j] = __builtin_amdgcn_mfma_f32_16x16x32_bf16(af[i], bfv[j], acc[i][j], 0, 0, 0);
        }
    }

    #pragma unroll
    for (int i = 0; i < MI; i++) {
        #pragma unroll
        for (int j = 0; j < 4; j++) {
            int nl = n0 + 64 * wn + 16 * j + l16;
            float bval = 0.0f;
            if (MODE != EP_QKV) bval = bias[nl];
            #pragma unroll
            for (int r = 0; r < 4; r++) {
                int ml = m0 + 16 * MI * wm + 16 * i + quad * 4 + r;
                float v = acc[i][j][r];
                if (MODE == EP_QKV) {
                    int which = nl >> 10, rem = nl & 1023;
                    int hh = rem >> 6, d = rem & 63;
                    int bb = ml >> 11, t = ml & 2047;
                    int bh = bb * HEADS + hh;
                    // q pre-scale = (1/8) * log2(e) so softmax is a bare v_exp_f32 (2^x)
                    if (which == 0)      q_buf[((size_t)bh * SEQ + t) * HD + d] = f2bf(v * 0.18033688011112042f);
                    else if (which == 1) k_buf[((size_t)bh * SEQ + t) * HD + d] = f2bf(v);
                    else                 v_buf[((size_t)bh * SEQ + t) * HD + d] = f2bf(v);
                } else if (MODE == EP_PROJ) {
                    float* x1 = (float*)out0;
                    x1[(size_t)ml * DIMC + nl] = res[(size_t)ml * DIMC + nl] + v + bval;
                } else if (MODE == EP_FC1) {
                    float g = v + bval;
                    float u = 1.5957691216f * (g + 0.044715f * g * g * g);
                    float gv = g / (1.0f + __expf(-u));
                    ((unsigned short*)out0)[(size_t)ml * HIDDENC + nl] = f2bf(gv);
                } else {
                    ((float*)out0)[(size_t)ml * DIMC + nl] =
                        res[(size_t)ml * DIMC + nl] + v + bval;
                }
            }
        }
    }
}

// ---------------------------------------------------------------------------
// Split-K flash attention partials. No online max (|s|<~7 after LN).
// Key-padding semantics MUST match the reference's fp32 "+(-1e9)":
// all masked scores collapse to the SAME value (uniform softmax when a row's
// visible keys are all masked). So masked keys get a CONSTANT weight 1e-13:
// normal rows see <=1e-7 relative perturbation; all-masked rows get
// exactly-uniform weights, matching ref. Partials combine by plain summation.
//
// This round: SWAPPED QK^T (S^T = mfma(K,Q)). C-layout then gives each lane
// one q (=l16) and 4 CONSECUTIVE keys (16ct+4quad+r), so:
//  - P-store = 2x v_cvt_pk_bf16_f32 + 1x ds_write_b64 per ct (vs 16 f2bf +
//    16 scalar b16 writes per tile);
//  - PV A-read stays the original contiguous ds_read_b128 (row-major Ps[q][k],
//    XOR-16B swizzled, write & read swizzle by the same row => consistent);
//  - lsum is a single scalar per lane, reduced with 2 shfl_xor (16,32);
//  - mask flags load as one float4 per ct.
// LDS 26880 B -> 6 blocks/CU (launch_bounds(256,6)).
// ---------------------------------------------------------------------------
#define KP 72
#define PMASK 1e-13f
__global__ __launch_bounds__(256, 6) void attn_partial(
    const unsigned short* __restrict__ q_buf,
    const unsigned short* __restrict__ k_buf,
    const unsigned short* __restrict__ vT_buf,
    const int* __restrict__ mask,
    unsigned short* __restrict__ opart0,   // d_out scratch (bh 0..24)
    unsigned short* __restrict__ opart1,   // x1 scratch (bh 25..31)
    float* __restrict__ l_part) {
    __shared__ __align__(16) unsigned short Ks[64 * KP];
    __shared__ __align__(16) unsigned short Vs[64 * KP];
    __shared__ __align__(16) unsigned short Ps[4 * 16 * 64];  // per-wave swizzled P[q][key]
    __shared__ __align__(16) float Msf[64];
    // slot -> (qt, chunk)
    const int slot = blockIdx.x;
    int s = slot, qt, c;
    if (s < 8)       { qt = s;              c = 0;     }
    else if (s < 24) { s -= 8;  qt = 8  + (s >> 1); c = s & 1; }
    else if (s < 48) { s -= 24; qt = 16 + s / 3;    c = s % 3; }
    else             { s -= 48; qt = 24 + (s >> 2); c = s & 3; }
    const int kt0 = c * 8;
    const int kt1 = min(kt0 + 8, qt + 1);

    const int h = blockIdx.y, bb = blockIdx.z;
    const int tid = threadIdx.x, wave = tid >> 6, lane = tid & 63;
    const int quad = lane >> 4, l16 = lane & 15;
    const int bh = bb * HEADS + h;
    const unsigned short* qp = q_buf + (size_t)bh * SEQ * HD;
    const unsigned short* kp = k_buf + (size_t)bh * SEQ * HD;
    const unsigned short* vp = vT_buf + (size_t)bh * HD * SEQ;
    const int* mrow_ptr = mask + bb * SEQ;

    const int qrow = qt * 64 + wave * 16 + l16;   // this lane's q (global)
    bf16x8 qf[2];
    qf[0] = *(const bf16x8*)(qp + (size_t)qrow * HD + 8 * quad);
    qf[1] = *(const bf16x8*)(qp + (size_t)qrow * HD + 32 + 8 * quad);

    f32x4 o[4] = {};
    float lsum = 0.0f;

    const int r0 = tid >> 3, c0 = (tid & 7) * 8;
    const int r1 = r0 + 32;

    // per-wave swizzled Ps addressing (bytes): row = q = l16, 128 B rows
    char* psb = (char*)Ps + wave * 2048 + l16 * 128;
    const int swz = (l16 & 7) << 4;

    // prefetch first tile of the chunk; Msf holds 1.0 = masked, 0.0 = visible
    uint4 pk0, pk1, pv0, pv1; float pmv = 0.0f;
    pk0 = *(const uint4*)(kp + (size_t)(kt0 * 64 + r0) * HD + c0);
    pk1 = *(const uint4*)(kp + (size_t)(kt0 * 64 + r1) * HD + c0);
    pv0 = *(const uint4*)(vp + (size_t)r0 * SEQ + kt0 * 64 + c0);
    pv1 = *(const uint4*)(vp + (size_t)r1 * SEQ + kt0 * 64 + c0);
    if (tid < 64) pmv = mrow_ptr[kt0 * 64 + tid] ? 1.0f : 0.0f;

    for (int kt = kt0; kt < kt1; kt++) {
        __syncthreads();
        *(uint4*)&Ks[r0 * KP + c0] = pk0;
        *(uint4*)&Ks[r1 * KP + c0] = pk1;
        *(uint4*)&Vs[r0 * KP + c0] = pv0;
        *(uint4*)&Vs[r1 * KP + c0] = pv1;
        if (tid < 64) Msf[tid] = pmv;
        if (kt + 1 < kt1) {
            pk0 = *(const uint4*)(kp + (size_t)((kt + 1) * 64 + r0) * HD + c0);
            pk1 = *(const uint4*)(kp + (size_t)((kt + 1) * 64 + r1) * HD + c0);
            pv0 = *(const uint4*)(vp + (size_t)r0 * SEQ + (kt + 1) * 64 + c0);
            pv1 = *(const uint4*)(vp + (size_t)r1 * SEQ + (kt + 1) * 64 + c0);
            if (tid < 64) pmv = mrow_ptr[(kt + 1) * 64 + tid] ? 1.0f : 0.0f;
        }
        __syncthreads();

        // S^T = K @ Q^T : sc[ct][r] = S[key=16ct+4quad+r][q=l16]
        f32x4 sc[4];
        __builtin_amdgcn_s_setprio(1);
        #pragma unroll
        for (int ct = 0; ct < 4; ct++) {
            f32x4 z = {};
            #pragma unroll
            for (int ss = 0; ss < 2; ss++) {
                bf16x8 kf = *(const bf16x8*)&Ks[(16 * ct + l16) * KP + 32 * ss + 8 * quad];
                z = __builtin_amdgcn_mfma_f32_16x16x32_bf16(kf, qf[ss], z, 0, 0, 0);
            }
            sc[ct] = z;
        }
        __builtin_amdgcn_s_setprio(0);

        const bool diag = (kt == qt);
        #pragma unroll
        for (int ct = 0; ct < 4; ct++) {
            float4 mq = *(const float4*)&Msf[16 * ct + 4 * quad];
            float mfs[4] = {mq.x, mq.y, mq.z, mq.w};
            const int kg0 = kt * 64 + 16 * ct + 4 * quad;
            float pv4[4];
            #pragma unroll
            for (int r = 0; r < 4; r++) {
                float p = (mfs[r] != 0.0f) ? PMASK : exp2_fast(sc[ct][r]);
                if (diag && (kg0 + r) > qrow) p = 0.0f;
                lsum += p;
                pv4[r] = p;
            }
            uint2 w;
            w.x = cvt_pk_bf16(pv4[0], pv4[1]);
            w.y = cvt_pk_bf16(pv4[2], pv4[3]);
            // P[q=l16][key=16ct+4quad .. +3]: logical byte quad*8+ct*32, swizzled
            *(uint2*)(psb + ((quad * 8 + ct * 32) ^ swz)) = w;
        }
        asm volatile("" ::: "memory");   // order punned LDS write -> read

        __builtin_amdgcn_s_setprio(1);
        #pragma unroll
        for (int ss = 0; ss < 2; ss++) {
            bf16x8 pf = *(const bf16x8*)(psb + ((ss * 64 + quad * 16) ^ swz));
            #pragma unroll
            for (int dt = 0; dt < 4; dt++) {
                bf16x8 vf = *(const bf16x8*)&Vs[(16 * dt + l16) * KP + 32 * ss + 8 * quad];
                o[dt] = __builtin_amdgcn_mfma_f32_16x16x32_bf16(pf, vf, o[dt], 0, 0, 0);
            }
        }
        __builtin_amdgcn_s_setprio(0);
    }

    // row-sum for q=l16 lives replicated across quads: butterfly over quads
    lsum += __shfl_xor(lsum, 16);
    lsum += __shfl_xor(lsum, 32);
    if (lane < 16)
        l_part[((size_t)bh * NSLOT + slot) * 64 + wave * 16 + lane] = lsum;

    unsigned short* ob = opart_base(opart0, opart1, bh) + (size_t)slot * 4096;
    #pragma unroll
    for (int dt = 0; dt < 4; dt++)
        #pragma unroll
        for (int r = 0; r < 4; r++)
            ob[(wave * 16 + quad * 4 + r) * 64 + 16 * dt + l16] = f2bf(o[dt][r]);
}

// ---------------------------------------------------------------------------
// Combine partials: attn_o[bh][t][d] = (sum_c O_c) / (sum_c l_c), bf16.
// One block per (qt, h, b).
// ---------------------------------------------------------------------------
__global__ __launch_bounds__(256) void attn_combine(
    const unsigned short* __restrict__ opart0,
    const unsigned short* __restrict__ opart1,
    const float* __restrict__ l_part,
    unsigned short* __restrict__ attn_o) {
    const int qt = blockIdx.x, h = blockIdx.y, bb = blockIdx.z;
    const int bh = bb * HEADS + h;
    const int g = qt >> 3;
    const int n = g + 1;
    const int baseB[4] = {0, 8, 24, 48};
    const int slot0 = baseB[g] + (qt - 8 * g) * n;
    const int tid = threadIdx.x;
    __shared__ float linv[64];
    if (tid < 64) {
        float acc = 0.0f;
        for (int cc = 0; cc < n; cc++)
            acc += l_part[((size_t)bh * NSLOT + slot0 + cc) * 64 + tid];
        linv[tid] = 1.0f / acc;
    }
    __syncthreads();
    const unsigned short* ob = opart_base((unsigned short*)opart0, (unsigned short*)opart1, bh)
                               + (size_t)slot0 * 4096;
    #pragma unroll
    for (int i = 0; i < 16; i++) {
        int idx = i * 256 + tid;          // 0..4095
        int row = idx >> 6, d = idx & 63;
        float acc = 0.0f;
        for (int cc = 0; cc < n; cc++)
            acc += bf2f(ob[(size_t)cc * 4096 + idx]);
        attn_o[((size_t)(bb * SEQ + qt * 64 + row)) * DIMC + h * HD + d] =
            f2bf(acc * linv[row]);
    }
}

// ---------------------------------------------------------------------------
extern "C" void kernel_launch(void* const* d_in, const int* in_sizes, int n_in,
                              void* d_out, int out_size, void* d_ws, size_t ws_size,
                              hipStream_t stream) {
    const float* x     = (const float*)d_in[0];
    const int*   mask  = (const int*)d_in[1];
    const float* ln1w  = (const float*)d_in[2];
    const float* ln1b  = (const float*)d_in[3];
    const float* qkvw  = (const float*)d_in[4];
    const float* projw = (const float*)d_in[5];
    const float* projb = (const float*)d_in[6];
    const float* ln2w  = (const float*)d_in[7];
    const float* ln2b  = (const float*)d_in[8];
    const float* fc1w  = (const float*)d_in[9];
    const float* fc1b  = (const float*)d_in[10];
    const float* fc2w  = (const float*)d_in[11];
    const float* fc2b  = (const float*)d_in[12];

    // Workspace (80 MB, lifetime reuse):
    //  [0,6M)    qkv_wT (dead after QKV gemm) | l_part [0,640K) during attn
    //  [6,8M)    proj_wT
    //  [8,16M)   fc1_wT
    //  [16,24M)  fc2_wT
    //  [24,32M)  ln_buf (ln1, later ln2)
    //  [32,40M)  q_buf   | h_buf [32,64M) at FC1
    //  [40,48M)  k_buf
    //  [48,56M)  v_buf -> attn_o (combine output)
    //  [56,64M)  vT_buf
    //  [64,80M)  O_part overflow (bh 25..31, 4.6M) during attn; x1 fp32 after
    // d_out (16.8M fp32 out): O_part scratch (bh 0..24) until FC2 overwrites.
    char* base = (char*)d_ws;
    unsigned short* qkv_wT  = (unsigned short*)(base);
    float*          l_part  = (float*)(base);                              // alias, post-QKV
    unsigned short* proj_wT = (unsigned short*)(base + (size_t)6  * 1024 * 1024);
    unsigned short* fc1_wT  = (unsigned short*)(base + (size_t)8  * 1024 * 1024);
    unsigned short* fc2_wT  = (unsigned short*)(base + (size_t)16 * 1024 * 1024);
    unsigned short* ln_buf  = (unsigned short*)(base + (size_t)24 * 1024 * 1024);
    unsigned short* q_buf   = (unsigned short*)(base + (size_t)32 * 1024 * 1024);
    unsigned short* k_buf   = (unsigned short*)(base + (size_t)40 * 1024 * 1024);
    unsigned short* v_buf   = (unsigned short*)(base + (size_t)48 * 1024 * 1024);
    unsigned short* attn_o  = (unsigned short*)(base + (size_t)48 * 1024 * 1024); // alias v_buf
    unsigned short* vT_buf  = (unsigned short*)(base + (size_t)56 * 1024 * 1024);
    unsigned short* h_buf   = (unsigned short*)(base + (size_t)32 * 1024 * 1024); // reuse
    float*          x1      = (float*)(base + (size_t)64 * 1024 * 1024);
    unsigned short* opart1  = (unsigned short*)(base + (size_t)64 * 1024 * 1024); // alias x1
    unsigned short* opart0  = (unsigned short*)d_out;                             // scratch until FC2

    // 1. all 4 weight transposes in one launch
    fused_transpose<<<3072, 256, 0, stream>>>(qkvw, projw, fc1w, fc2w,
                                              qkv_wT, proj_wT, fc1_wT, fc2_wT);

    // 2. LN1 (fp32 x -> bf16)
    ln_kernel<<<MTOK, 256, 0, stream>>>(x, ln1w, ln1b, ln_buf);

    // 3. QKV GEMM -> q (pre-scaled by log2e/8), k, v (all [bh][t][d])
    gemm_kernel<EP_QKV, 3072, 1024, 128, 64><<<dim3(24, 32), 256, 0, stream>>>(
        ln_buf, qkv_wT, nullptr, nullptr, nullptr, q_buf, k_buf, v_buf);

    // 4. V transpose -> vT [bh][d][t]
    transpose_v<<<dim3(SEQ / 64, BATCH * HEADS), 256, 0, stream>>>(v_buf, vT_buf);

    // 5a. split-K attention partials (2560 blocks)
    attn_partial<<<dim3(NSLOT, HEADS, BATCH), 256, 0, stream>>>(
        q_buf, k_buf, vT_buf, mask, opart0, opart1, l_part);

    // 5b. combine -> attn_o (aliases v_buf, dead now)
    attn_combine<<<dim3(SEQ / 64, HEADS, BATCH), 256, 0, stream>>>(
        opart0, opart1, l_part, attn_o);

    // 6. proj GEMM + residual(x fp32) -> x1 (fp32; O_part overflow dead now)
    gemm_kernel<EP_PROJ, 1024, 1024, 64, 64><<<dim3(8, 64), 256, 0, stream>>>(
        attn_o, proj_wT, projb, x, x1, nullptr, nullptr, nullptr);

    // 7. LN2 (fp32 x1 -> bf16)
    ln_kernel<<<MTOK, 256, 0, stream>>>(x1, ln2w, ln2b, ln_buf);

    // 8. FC1 + GELU -> h_buf (bf16)
    gemm_kernel<EP_FC1, 4096, 1024, 128, 64><<<dim3(32, 32), 256, 0, stream>>>(
        ln_buf, fc1_wT, fc1b, nullptr, h_buf, nullptr, nullptr, nullptr);

    // 9. FC2 + residual(x1) -> d_out (fp32; overwrites O_part scratch fully)
    gemm_kernel<EP_FC2, 1024, 4096, 64, 64><<<dim3(8, 64), 256, 0, stream>>>(
        h_buf, fc2_wT, fc2b, x1, d_out, nullptr, nullptr, nullptr);
}

// Round 3
// 390.264 us; speedup vs baseline: 1.0331x; 1.0331x over previous
//
#include <hip/hip_runtime.h>
#include <stdint.h>

#define DIMC 1024
#define HEADS 16
#define HD 64
#define HIDDENC 4096
#define BATCH 2
#define SEQ 2048
#define MTOK (BATCH*SEQ)
#define NSLOT 80            // split-K chunk slots per (b,h): 8*1+8*2+8*3+8*4
#define BH_ELEMS (NSLOT*64*64)   // bf16 elems of O_part per bh = 327680

typedef __bf16 bf16x8 __attribute__((ext_vector_type(8)));
typedef float f32x4 __attribute__((ext_vector_type(4)));

__device__ __forceinline__ float bf2f(unsigned short u) {
    union { unsigned int u; float f; } v; v.u = ((unsigned int)u) << 16; return v.f;
}
__device__ __forceinline__ unsigned short f2bf(float f) {
    union { float f; unsigned int u; } v; v.f = f;
    unsigned int r = v.u + 0x7fffu + ((v.u >> 16) & 1u);
    return (unsigned short)(r >> 16);
}
// pack 2 f32 -> 2 bf16 (RNE), src0 -> low half (T12 recipe, guide-verified)
__device__ __forceinline__ unsigned int cvt_pk_bf16(float lo, float hi) {
    unsigned int r;
    asm("v_cvt_pk_bf16_f32 %0, %1, %2" : "=v"(r) : "v"(lo), "v"(hi));
    return r;
}
// 2^x (log2e is pre-folded into the Q scale)
__device__ __forceinline__ float exp2_fast(float x) {
#if __has_builtin(__builtin_amdgcn_exp2f)
    return __builtin_amdgcn_exp2f(x);
#else
    float r;
    asm("v_exp_f32 %0, %1" : "=v"(r) : "v"(x));
    return r;
#endif
}

#define GLOAD_LDS(g, l) \
    __builtin_amdgcn_global_load_lds( \
        (const __attribute__((address_space(1))) void*)(g), \
        (__attribute__((address_space(3))) void*)(l), 16, 0, 0)

// O_part is split across d_out (first 25 bh) and the x1 region (last 7 bh).
__device__ __forceinline__ unsigned short* opart_base(
    unsigned short* o0, unsigned short* o1, int bh) {
    return (bh < 25) ? (o0 + (size_t)bh * BH_ELEMS)
                     : (o1 + (size_t)(bh - 25) * BH_ELEMS);
}

// ---------------------------------------------------------------------------
// Fused weight transposes: fp32 (K x N) -> bf16 (N x K) for all 4 weights.
// ---------------------------------------------------------------------------
__device__ __forceinline__ void tp_tile(const float* __restrict__ in,
                                        unsigned short* __restrict__ out,
                                        int K, int N, int tn, int tk, int tid,
                                        unsigned short (*tile)[65]) {
    for (int c = tid; c < 1024; c += 256) {
        int r = c >> 4, coff = (c & 15) * 4;
        float4 v = *(const float4*)(in + (size_t)(tk + r) * N + tn + coff);
        tile[r][coff + 0] = f2bf(v.x);
        tile[r][coff + 1] = f2bf(v.y);
        tile[r][coff + 2] = f2bf(v.z);
        tile[r][coff + 3] = f2bf(v.w);
    }
    __syncthreads();
    for (int c = tid; c < 512; c += 256) {
        int rn = c >> 3, off = (c & 7) * 8;
        unsigned short tmp[8];
        #pragma unroll
        for (int j = 0; j < 8; j++) tmp[j] = tile[off + j][rn];
        *(uint4*)(out + (size_t)(tn + rn) * K + tk + off) = *(uint4*)tmp;
    }
}

__global__ __launch_bounds__(256) void fused_transpose(
    const float* __restrict__ qkvw, const float* __restrict__ projw,
    const float* __restrict__ fc1w, const float* __restrict__ fc2w,
    unsigned short* __restrict__ qkv_wT, unsigned short* __restrict__ proj_wT,
    unsigned short* __restrict__ fc1_wT, unsigned short* __restrict__ fc2_wT) {
    __shared__ unsigned short tile[64][65];
    int id = blockIdx.x, tid = threadIdx.x;
    if (id < 768) {
        tp_tile(qkvw, qkv_wT, 1024, 3072, (id % 48) * 64, (id / 48) * 64, tid, tile);
    } else if (id < 1024) {
        id -= 768;
        tp_tile(projw, proj_wT, 1024, 1024, (id % 16) * 64, (id / 16) * 64, tid, tile);
    } else if (id < 2048) {
        id -= 1024;
        tp_tile(fc1w, fc1_wT, 1024, 4096, (id % 64) * 64, (id / 64) * 64, tid, tile);
    } else {
        id -= 2048;
        tp_tile(fc2w, fc2_wT, 4096, 1024, (id % 16) * 64, (id / 16) * 64, tid, tile);
    }
}

// ---------------------------------------------------------------------------
// Per-head V transpose: v_buf (bh, t, d) -> vT_buf (bh, d, t), bf16.
// ---------------------------------------------------------------------------
__global__ __launch_bounds__(256) void transpose_v(const unsigned short* __restrict__ in,
                                                   unsigned short* __restrict__ out) {
    __shared__ unsigned short tile[64][65];
    int t0 = blockIdx.x * 64;
    int bh = blockIdx.y;
    const unsigned short* ip = in + (size_t)bh * SEQ * HD;
    unsigned short* op = out + (size_t)bh * HD * SEQ;
    int tid = threadIdx.x;
    for (int c = tid; c < 512; c += 256) {
        int r = c >> 3, off = (c & 7) * 8;
        *(uint4*)&tile[r][off] = *(const uint4*)(ip + (size_t)(t0 + r) * HD + off);
    }
    __syncthreads();
    for (int c = tid; c < 512; c += 256) {
        int rn = c >> 3, off = (c & 7) * 8;
        unsigned short tmp[8];
        #pragma unroll
        for (int j = 0; j < 8; j++) tmp[j] = tile[off + j][rn];
        *(uint4*)(op + (size_t)rn * SEQ + t0 + off) = *(uint4*)tmp;
    }
}

// ---------------------------------------------------------------------------
// LayerNorm: f32 input, f32 w/b, bf16 output. One block per row (DIMC=1024).
// ---------------------------------------------------------------------------
__global__ __launch_bounds__(256) void ln_kernel(const float* __restrict__ inp,
                                                 const float* __restrict__ w,
                                                 const float* __restrict__ b,
                                                 unsigned short* __restrict__ out) {
    int row = blockIdx.x;
    int tid = threadIdx.x;
    int base = tid * 4;
    float4 v = *(const float4*)(inp + (size_t)row * DIMC + base);
    float x[4] = {v.x, v.y, v.z, v.w};
    float s1 = x[0] + x[1] + x[2] + x[3];
    float s2 = x[0]*x[0] + x[1]*x[1] + x[2]*x[2] + x[3]*x[3];
    #pragma unroll
    for (int off = 32; off > 0; off >>= 1) {
        s1 += __shfl_xor(s1, off);
        s2 += __shfl_xor(s2, off);
    }
    __shared__ float red[8];
    int wv = tid >> 6;
    if ((tid & 63) == 0) { red[wv] = s1; red[4 + wv] = s2; }
    __syncthreads();
    s1 = red[0] + red[1] + red[2] + red[3];
    s2 = red[4] + red[5] + red[6] + red[7];
    float mean = s1 * (1.0f / DIMC);
    float var  = s2 * (1.0f / DIMC) - mean * mean;
    float rstd = rsqrtf(var + 1e-5f);
    float4 wv4 = *(const float4*)(w + base);
    float4 bv4 = *(const float4*)(b + base);
    ushort4 o;
    o.x = f2bf((x[0] - mean) * rstd * wv4.x + bv4.x);
    o.y = f2bf((x[1] - mean) * rstd * wv4.y + bv4.y);
    o.z = f2bf((x[2] - mean) * rstd * wv4.z + bv4.z);
    o.w = f2bf((x[3] - mean) * rstd * wv4.w + bv4.w);
    *(ushort4*)(out + (size_t)row * DIMC + base) = o;
}

// ---------------------------------------------------------------------------
// bf16 MFMA GEMM: C(M x N) = A(M x K) @ BT(N x K)^T.
// Tile TM x 128, BK-deep staging via global_load_lds, 4 waves (2x2).
// XOR-swizzled LDS layout -> conflict-free ds_read_b128.
// ---------------------------------------------------------------------------
enum { EP_QKV = 0, EP_PROJ = 1, EP_FC1 = 2, EP_FC2 = 3 };

template <int MODE, int N, int K, int TM, int BK>
__global__ __launch_bounds__(256) void gemm_kernel(
    const unsigned short* __restrict__ A,
    const unsigned short* __restrict__ BT,
    const float* __restrict__ bias,
    const float* __restrict__ res,      // fp32 residual (PROJ: x, FC2: x1)
    void* __restrict__ out0,
    unsigned short* __restrict__ q_buf,
    unsigned short* __restrict__ k_buf,
    unsigned short* __restrict__ v_buf) {
    constexpr int MI = TM / 32;
    constexpr int CPR = BK / 8;
    __shared__ __align__(16) unsigned short As[TM * BK];
    __shared__ __align__(16) unsigned short Bs[128 * BK];
    const int tid = threadIdx.x;
    const int m0 = blockIdx.y * TM;
    const int n0 = blockIdx.x * 128;
    const int wave = tid >> 6, lane = tid & 63;
    const int wm = wave >> 1, wn = wave & 1;
    const int quad = lane >> 4, l16 = lane & 15;
    const int swz = l16 & (CPR - 1);

    f32x4 acc[MI][4] = {};

    for (int kk = 0; kk < K; kk += BK) {
        __syncthreads();
        #pragma unroll
        for (int it = 0; it < TM * BK / 2048; ++it) {
            int c = tid + 256 * it;
            int row = c / CPR, jj = c % CPR;
            int col8 = (jj ^ (row & (CPR - 1))) * 8;
            GLOAD_LDS(A + (size_t)(m0 + row) * K + kk + col8, As + (size_t)c * 8);
        }
        #pragma unroll
        for (int it = 0; it < 128 * BK / 2048; ++it) {
            int c = tid + 256 * it;
            int row = c / CPR, jj = c % CPR;
            int col8 = (jj ^ (row & (CPR - 1))) * 8;
            GLOAD_LDS(BT + (size_t)(n0 + row) * K + kk + col8, Bs + (size_t)c * 8);
        }
        __syncthreads();
        #pragma unroll
        for (int kk2 = 0; kk2 < BK / 32; ++kk2) {
            bf16x8 af[MI], bfv[4];
            #pragma unroll
            for (int i = 0; i < MI; i++) {
                int row = 16 * MI * wm + 16 * i + l16;
                int sj = (4 * kk2 + quad) ^ swz;
                af[i] = *(const bf16x8*)&As[row * BK + sj * 8];
            }
            #pragma unroll
            for (int j = 0; j < 4; j++) {
                int row = 64 * wn + 16 * j + l16;
                int sj = (4 * kk2 + quad) ^ swz;
                bfv[j] = *(const bf16x8*)&Bs[row * BK + sj * 8];
            }
            #pragma unroll
            for (int i = 0; i < MI; i++)
                #pragma unroll
                for (int j = 0; j < 4; j++)
                    acc[i][j] = __builtin_amdgcn_mfma_f32_16x16x32_bf16(af[i], bfv[j], acc[i][j], 0, 0, 0);
        }
    }

    #pragma unroll
    for (int i = 0; i < MI; i++) {
        #pragma unroll
        for (int j = 0; j < 4; j++) {
            int nl = n0 + 64 * wn + 16 * j + l16;
            float bval = 0.0f;
            if (MODE != EP_QKV) bval = bias[nl];
            #pragma unroll
            for (int r = 0; r < 4; r++) {
                int ml = m0 + 16 * MI * wm + 16 * i + quad * 4 + r;
                float v = acc[i][j][r];
                if (MODE == EP_QKV) {
                    int which = nl >> 10, rem = nl & 1023;
                    int hh = rem >> 6, d = rem & 63;
                    int bb = ml >> 11, t = ml & 2047;
                    int bh = bb * HEADS + hh;
                    // q pre-scale = (1/8) * log2(e) so softmax is a bare v_exp_f32 (2^x)
                    if (which == 0)      q_buf[((size_t)bh * SEQ + t) * HD + d] = f2bf(v * 0.18033688011112042f);
                    else if (which == 1) k_buf[((size_t)bh * SEQ + t) * HD + d] = f2bf(v);
                    else                 v_buf[((size_t)bh * SEQ + t) * HD + d] = f2bf(v);
                } else if (MODE == EP_PROJ) {
                    float* x1 = (float*)out0;
                    x1[(size_t)ml * DIMC + nl] = res[(size_t)ml * DIMC + nl] + v + bval;
                } else if (MODE == EP_FC1) {
                    float g = v + bval;
                    float u = 1.5957691216f * (g + 0.044715f * g * g * g);
                    float gv = g / (1.0f + __expf(-u));
                    ((unsigned short*)out0)[(size_t)ml * HIDDENC + nl] = f2bf(gv);
                } else {
                    ((float*)out0)[(size_t)ml * DIMC + nl] =
                        res[(size_t)ml * DIMC + nl] + v + bval;
                }
            }
        }
    }
}

// ---------------------------------------------------------------------------
// Split-K flash attention partials. No online max (|s|<~7 after LN).
// Key-padding semantics MUST match the reference's fp32 "+(-1e9)":
// all masked scores collapse to the SAME value (uniform softmax when a row's
// visible keys are all masked). So masked keys get a CONSTANT weight 1e-13:
// normal rows see <=1e-7 relative perturbation; all-masked rows get
// exactly-uniform weights, matching ref. Partials combine by plain summation.
//
// Swapped QK^T (S^T = mfma(K,Q)): lane holds one q (=l16) and 4 consecutive
// keys -> P-store = 2x cvt_pk + 1x ds_write_b64 per ct; PV A-read is a
// contiguous ds_read_b128 from the XOR-swizzled row-major Ps[q][key].
//
// Round 3 fixes (counter-driven):
//  - O_part store staged through the wave's private (dead) Ps region and
//    written as 2x global_store_dwordx4/lane (full-line coalesced).
//    R2 evidence: scalar b16 stores + 6 blocks/CU thrashed L2 partial lines
//    -> WRITE_SIZE 21MB -> 85MB. This restores write-once semantics.
//  - XCD-aware 1D swizzle: all 80 blocks of one (b,h) land on one XCD
//    (j = 8*(bg*80+slot)+xcd, bh = bg*8+xcd), so the shared 512KB K/V set
//    stays L2-resident per XCD (R2 FETCH inflation fix).
// ---------------------------------------------------------------------------
#define KP 72
#define PMASK 1e-13f
__global__ __launch_bounds__(256, 6) void attn_partial(
    const unsigned short* __restrict__ q_buf,
    const unsigned short* __restrict__ k_buf,
    const unsigned short* __restrict__ vT_buf,
    const int* __restrict__ mask,
    unsigned short* __restrict__ opart0,   // d_out scratch (bh 0..24)
    unsigned short* __restrict__ opart1,   // x1 scratch (bh 25..31)
    float* __restrict__ l_part) {
    __shared__ __align__(16) unsigned short Ks[64 * KP];
    __shared__ __align__(16) unsigned short Vs[64 * KP];
    __shared__ __align__(16) unsigned short Ps[4 * 16 * 64];  // per-wave swizzled P[q][key]; O-stage after loop
    __shared__ __align__(16) float Msf[64];

    // XCD-aware decode: consecutive blockIdx round-robin XCDs; keep all 80
    // slots of one bh on one XCD. Bijective on [0,2560).
    const int j = blockIdx.x;
    const int xcd = j & 7;
    const int t = j >> 3;            // 0..319
    const int slot = t % NSLOT;
    const int bg = t / NSLOT;        // 0..3
    const int bh = bg * 8 + xcd;     // 0..31
    const int bb = bh >> 4, h = bh & 15;

    // slot -> (qt, chunk)
    int s = slot, qt, c;
    if (s < 8)       { qt = s;              c = 0;     }
    else if (s < 24) { s -= 8;  qt = 8  + (s >> 1); c = s & 1; }
    else if (s < 48) { s -= 24; qt = 16 + s / 3;    c = s % 3; }
    else             { s -= 48; qt = 24 + (s >> 2); c = s & 3; }
    const int kt0 = c * 8;
    const int kt1 = min(kt0 + 8, qt + 1);

    const int tid = threadIdx.x, wave = tid >> 6, lane = tid & 63;
    const int quad = lane >> 4, l16 = lane & 15;
    const unsigned short* qp = q_buf + (size_t)bh * SEQ * HD;
    const unsigned short* kp = k_buf + (size_t)bh * SEQ * HD;
    const unsigned short* vp = vT_buf + (size_t)bh * HD * SEQ;
    const int* mrow_ptr = mask + bb * SEQ;

    const int qrow = qt * 64 + wave * 16 + l16;   // this lane's q (global)
    bf16x8 qf[2];
    qf[0] = *(const bf16x8*)(qp + (size_t)qrow * HD + 8 * quad);
    qf[1] = *(const bf16x8*)(qp + (size_t)qrow * HD + 32 + 8 * quad);

    f32x4 o[4] = {};
    float lsum = 0.0f;

    const int r0 = tid >> 3, c0 = (tid & 7) * 8;
    const int r1 = r0 + 32;

    // per-wave swizzled Ps addressing (bytes): row = q = l16, 128 B rows
    char* psb = (char*)Ps + wave * 2048 + l16 * 128;
    const int swz = (l16 & 7) << 4;

    // prefetch first tile of the chunk; Msf holds 1.0 = masked, 0.0 = visible
    uint4 pk0, pk1, pv0, pv1; float pmv = 0.0f;
    pk0 = *(const uint4*)(kp + (size_t)(kt0 * 64 + r0) * HD + c0);
    pk1 = *(const uint4*)(kp + (size_t)(kt0 * 64 + r1) * HD + c0);
    pv0 = *(const uint4*)(vp + (size_t)r0 * SEQ + kt0 * 64 + c0);
    pv1 = *(const uint4*)(vp + (size_t)r1 * SEQ + kt0 * 64 + c0);
    if (tid < 64) pmv = mrow_ptr[kt0 * 64 + tid] ? 1.0f : 0.0f;

    for (int kt = kt0; kt < kt1; kt++) {
        __syncthreads();
        *(uint4*)&Ks[r0 * KP + c0] = pk0;
        *(uint4*)&Ks[r1 * KP + c0] = pk1;
        *(uint4*)&Vs[r0 * KP + c0] = pv0;
        *(uint4*)&Vs[r1 * KP + c0] = pv1;
        if (tid < 64) Msf[tid] = pmv;
        if (kt + 1 < kt1) {
            pk0 = *(const uint4*)(kp + (size_t)((kt + 1) * 64 + r0) * HD + c0);
            pk1 = *(const uint4*)(kp + (size_t)((kt + 1) * 64 + r1) * HD + c0);
            pv0 = *(const uint4*)(vp + (size_t)r0 * SEQ + (kt + 1) * 64 + c0);
            pv1 = *(const uint4*)(vp + (size_t)r1 * SEQ + (kt + 1) * 64 + c0);
            if (tid < 64) pmv = mrow_ptr[(kt + 1) * 64 + tid] ? 1.0f : 0.0f;
        }
        __syncthreads();

        // S^T = K @ Q^T : sc[ct][r] = S[key=16ct+4quad+r][q=l16]
        f32x4 sc[4];
        __builtin_amdgcn_s_setprio(1);
        #pragma unroll
        for (int ct = 0; ct < 4; ct++) {
            f32x4 z = {};
            #pragma unroll
            for (int ss = 0; ss < 2; ss++) {
                bf16x8 kf = *(const bf16x8*)&Ks[(16 * ct + l16) * KP + 32 * ss + 8 * quad];
                z = __builtin_amdgcn_mfma_f32_16x16x32_bf16(kf, qf[ss], z, 0, 0, 0);
            }
            sc[ct] = z;
        }
        __builtin_amdgcn_s_setprio(0);

        const bool diag = (kt == qt);
        #pragma unroll
        for (int ct = 0; ct < 4; ct++) {
            float4 mq = *(const float4*)&Msf[16 * ct + 4 * quad];
            float mfs[4] = {mq.x, mq.y, mq.z, mq.w};
            const int kg0 = kt * 64 + 16 * ct + 4 * quad;
            float pv4[4];
            #pragma unroll
            for (int r = 0; r < 4; r++) {
                float p = (mfs[r] != 0.0f) ? PMASK : exp2_fast(sc[ct][r]);
                if (diag && (kg0 + r) > qrow) p = 0.0f;
                lsum += p;
                pv4[r] = p;
            }
            uint2 w;
            w.x = cvt_pk_bf16(pv4[0], pv4[1]);
            w.y = cvt_pk_bf16(pv4[2], pv4[3]);
            // P[q=l16][key=16ct+4quad .. +3]: logical byte quad*8+ct*32, swizzled
            *(uint2*)(psb + ((quad * 8 + ct * 32) ^ swz)) = w;
        }
        asm volatile("" ::: "memory");   // order punned LDS write -> read

        __builtin_amdgcn_s_setprio(1);
        #pragma unroll
        for (int ss = 0; ss < 2; ss++) {
            bf16x8 pf = *(const bf16x8*)(psb + ((ss * 64 + quad * 16) ^ swz));
            #pragma unroll
            for (int dt = 0; dt < 4; dt++) {
                bf16x8 vf = *(const bf16x8*)&Vs[(16 * dt + l16) * KP + 32 * ss + 8 * quad];
                o[dt] = __builtin_amdgcn_mfma_f32_16x16x32_bf16(pf, vf, o[dt], 0, 0, 0);
            }
        }
        __builtin_amdgcn_s_setprio(0);
    }

    // row-sum for q=l16 lives replicated across quads: butterfly over quads
    lsum += __shfl_xor(lsum, 16);
    lsum += __shfl_xor(lsum, 32);
    if (lane < 16)
        l_part[((size_t)bh * NSLOT + slot) * 64 + wave * 16 + lane] = lsum;

    // O store: stage the wave's 16x64 subtile in its private Ps region (dead
    // now), then write 2x dwordx4 per lane -> full-line coalesced HBM writes.
    unsigned short* Ls = Ps + wave * 1024;   // 16 rows x 64 cols bf16 = 2 KB
    #pragma unroll
    for (int dt = 0; dt < 4; dt++)
        #pragma unroll
        for (int r = 0; r < 4; r++)
            Ls[(quad * 4 + r) * 64 + 16 * dt + l16] = f2bf(o[dt][r]);
    asm volatile("" ::: "memory");           // order punned LDS write -> read
    unsigned short* ob = opart_base(opart0, opart1, bh)
                         + (size_t)slot * 4096 + wave * 1024;
    uint4 w0 = *(const uint4*)&Ls[lane * 8];
    uint4 w1 = *(const uint4*)&Ls[512 + lane * 8];
    *(uint4*)(ob + lane * 8) = w0;
    *(uint4*)(ob + 512 + lane * 8) = w1;
}

// ---------------------------------------------------------------------------
// Combine partials: attn_o[bh][t][d] = (sum_c O_c) / (sum_c l_c), bf16.
// One block per (qt, h, b).
// ---------------------------------------------------------------------------
__global__ __launch_bounds__(256) void attn_combine(
    const unsigned short* __restrict__ opart0,
    const unsigned short* __restrict__ opart1,
    const float* __restrict__ l_part,
    unsigned short* __restrict__ attn_o) {
    const int qt = blockIdx.x, h = blockIdx.y, bb = blockIdx.z;
    const int bh = bb * HEADS + h;
    const int g = qt >> 3;
    const int n = g + 1;
    const int baseB[4] = {0, 8, 24, 48};
    const int slot0 = baseB[g] + (qt - 8 * g) * n;
    const int tid = threadIdx.x;
    __shared__ float linv[64];
    if (tid < 64) {
        float acc = 0.0f;
        for (int cc = 0; cc < n; cc++)
            acc += l_part[((size_t)bh * NSLOT + slot0 + cc) * 64 + tid];
        linv[tid] = 1.0f / acc;
    }
    __syncthreads();
    const unsigned short* ob = opart_base((unsigned short*)opart0, (unsigned short*)opart1, bh)
                               + (size_t)slot0 * 4096;
    #pragma unroll
    for (int i = 0; i < 16; i++) {
        int idx = i * 256 + tid;          // 0..4095
        int row = idx >> 6, d = idx & 63;
        float acc = 0.0f;
        for (int cc = 0; cc < n; cc++)
            acc += bf2f(ob[(size_t)cc * 4096 + idx]);
        attn_o[((size_t)(bb * SEQ + qt * 64 + row)) * DIMC + h * HD + d] =
            f2bf(acc * linv[row]);
    }
}

// ---------------------------------------------------------------------------
extern "C" void kernel_launch(void* const* d_in, const int* in_sizes, int n_in,
                              void* d_out, int out_size, void* d_ws, size_t ws_size,
                              hipStream_t stream) {
    const float* x     = (const float*)d_in[0];
    const int*   mask  = (const int*)d_in[1];
    const float* ln1w  = (const float*)d_in[2];
    const float* ln1b  = (const float*)d_in[3];
    const float* qkvw  = (const float*)d_in[4];
    const float* projw = (const float*)d_in[5];
    const float* projb = (const float*)d_in[6];
    const float* ln2w  = (const float*)d_in[7];
    const float* ln2b  = (const float*)d_in[8];
    const float* fc1w  = (const float*)d_in[9];
    const float* fc1b  = (const float*)d_in[10];
    const float* fc2w  = (const float*)d_in[11];
    const float* fc2b  = (const float*)d_in[12];

    // Workspace (80 MB, lifetime reuse):
    //  [0,6M)    qkv_wT (dead after QKV gemm) | l_part [0,640K) during attn
    //  [6,8M)    proj_wT
    //  [8,16M)   fc1_wT
    //  [16,24M)  fc2_wT
    //  [24,32M)  ln_buf (ln1, later ln2)
    //  [32,40M)  q_buf   | h_buf [32,64M) at FC1
    //  [40,48M)  k_buf
    //  [48,56M)  v_buf -> attn_o (combine output)
    //  [56,64M)  vT_buf
    //  [64,80M)  O_part overflow (bh 25..31, 4.6M) during attn; x1 fp32 after
    // d_out (16.8M fp32 out): O_part scratch (bh 0..24) until FC2 overwrites.
    char* base = (char*)d_ws;
    unsigned short* qkv_wT  = (unsigned short*)(base);
    float*          l_part  = (float*)(base);                              // alias, post-QKV
    unsigned short* proj_wT = (unsigned short*)(base + (size_t)6  * 1024 * 1024);
    unsigned short* fc1_wT  = (unsigned short*)(base + (size_t)8  * 1024 * 1024);
    unsigned short* fc2_wT  = (unsigned short*)(base + (size_t)16 * 1024 * 1024);
    unsigned short* ln_buf  = (unsigned short*)(base + (size_t)24 * 1024 * 1024);
    unsigned short* q_buf   = (unsigned short*)(base + (size_t)32 * 1024 * 1024);
    unsigned short* k_buf   = (unsigned short*)(base + (size_t)40 * 1024 * 1024);
    unsigned short* v_buf   = (unsigned short*)(base + (size_t)48 * 1024 * 1024);
    unsigned short* attn_o  = (unsigned short*)(base + (size_t)48 * 1024 * 1024); // alias v_buf
    unsigned short* vT_buf  = (unsigned short*)(base + (size_t)56 * 1024 * 1024);
    unsigned short* h_buf   = (unsigned short*)(base + (size_t)32 * 1024 * 1024); // reuse
    float*          x1      = (float*)(base + (size_t)64 * 1024 * 1024);
    unsigned short* opart1  = (unsigned short*)(base + (size_t)64 * 1024 * 1024); // alias x1
    unsigned short* opart0  = (unsigned short*)d_out;                             // scratch until FC2

    // 1. all 4 weight transposes in one launch
    fused_transpose<<<3072, 256, 0, stream>>>(qkvw, projw, fc1w, fc2w,
                                              qkv_wT, proj_wT, fc1_wT, fc2_wT);

    // 2. LN1 (fp32 x -> bf16)
    ln_kernel<<<MTOK, 256, 0, stream>>>(x, ln1w, ln1b, ln_buf);

    // 3. QKV GEMM -> q (pre-scaled by log2e/8), k, v (all [bh][t][d])
    gemm_kernel<EP_QKV, 3072, 1024, 128, 64><<<dim3(24, 32), 256, 0, stream>>>(
        ln_buf, qkv_wT, nullptr, nullptr, nullptr, q_buf, k_buf, v_buf);

    // 4. V transpose -> vT [bh][d][t]
    transpose_v<<<dim3(SEQ / 64, BATCH * HEADS), 256, 0, stream>>>(v_buf, vT_buf);

    // 5a. split-K attention partials (2560 blocks, XCD-swizzled 1D grid)
    attn_partial<<<NSLOT * HEADS * BATCH, 256, 0, stream>>>(
        q_buf, k_buf, vT_buf, mask, opart0, opart1, l_part);

    // 5b. combine -> attn_o (aliases v_buf, dead now)
    attn_combine<<<dim3(SEQ / 64, HEADS, BATCH), 256, 0, stream>>>(
        opart0, opart1, l_part, attn_o);

    // 6. proj GEMM + residual(x fp32) -> x1 (fp32; O_part overflow dead now)
    gemm_kernel<EP_PROJ, 1024, 1024, 64, 64><<<dim3(8, 64), 256, 0, stream>>>(
        attn_o, proj_wT, projb, x, x1, nullptr, nullptr, nullptr);

    // 7. LN2 (fp32 x1 -> bf16)
    ln_kernel<<<MTOK, 256, 0, stream>>>(x1, ln2w, ln2b, ln_buf);

    // 8. FC1 + GELU -> h_buf (bf16)
    gemm_kernel<EP_FC1, 4096, 1024, 128, 64><<<dim3(32, 32), 256, 0, stream>>>(
        ln_buf, fc1_wT, fc1b, nullptr, h_buf, nullptr, nullptr, nullptr);

    // 9. FC2 + residual(x1) -> d_out (fp32; overwrites O_part scratch fully)
    gemm_kernel<EP_FC2, 1024, 4096, 64, 64><<<dim3(8, 64), 256, 0, stream>>>(
        h_buf, fc2_wT, fc2b, x1, d_out, nullptr, nullptr, nullptr);
}

// Round 4
// 389.661 us; speedup vs baseline: 1.0347x; 1.0015x over previous
//
#include <hip/hip_runtime.h>
#include <stdint.h>

#define DIMC 1024
#define HEADS 16
#define HD 64
#define HIDDENC 4096
#define BATCH 2
#define SEQ 2048
#define MTOK (BATCH*SEQ)
#define NSLOT 80            // split-K chunk slots per (b,h): 8*1+8*2+8*3+8*4
#define BH_ELEMS (NSLOT*64*64)   // bf16 elems of O_part per bh = 327680

typedef __bf16 bf16x8 __attribute__((ext_vector_type(8)));
typedef float f32x4 __attribute__((ext_vector_type(4)));

__device__ __forceinline__ float bf2f(unsigned short u) {
    union { unsigned int u; float f; } v; v.u = ((unsigned int)u) << 16; return v.f;
}
__device__ __forceinline__ unsigned short f2bf(float f) {
    union { float f; unsigned int u; } v; v.f = f;
    unsigned int r = v.u + 0x7fffu + ((v.u >> 16) & 1u);
    return (unsigned short)(r >> 16);
}
// pack 2 f32 -> 2 bf16 (RNE), src0 -> low half (T12 recipe, guide-verified)
__device__ __forceinline__ unsigned int cvt_pk_bf16(float lo, float hi) {
    unsigned int r;
    asm("v_cvt_pk_bf16_f32 %0, %1, %2" : "=v"(r) : "v"(lo), "v"(hi));
    return r;
}
// 2^x (log2e is pre-folded into the Q scale)
__device__ __forceinline__ float exp2_fast(float x) {
#if __has_builtin(__builtin_amdgcn_exp2f)
    return __builtin_amdgcn_exp2f(x);
#else
    float r;
    asm("v_exp_f32 %0, %1" : "=v"(r) : "v"(x));
    return r;
#endif
}

#define GLOAD_LDS(g, l) \
    __builtin_amdgcn_global_load_lds( \
        (const __attribute__((address_space(1))) void*)(g), \
        (__attribute__((address_space(3))) void*)(l), 16, 0, 0)

// O_part is split across d_out (first 25 bh) and the x1 region (last 7 bh).
__device__ __forceinline__ unsigned short* opart_base(
    unsigned short* o0, unsigned short* o1, int bh) {
    return (bh < 25) ? (o0 + (size_t)bh * BH_ELEMS)
                     : (o1 + (size_t)(bh - 25) * BH_ELEMS);
}

// ---------------------------------------------------------------------------
// Fused weight transposes: fp32 (K x N) -> bf16 (N x K) for all 4 weights.
// ---------------------------------------------------------------------------
__device__ __forceinline__ void tp_tile(const float* __restrict__ in,
                                        unsigned short* __restrict__ out,
                                        int K, int N, int tn, int tk, int tid,
                                        unsigned short (*tile)[65]) {
    for (int c = tid; c < 1024; c += 256) {
        int r = c >> 4, coff = (c & 15) * 4;
        float4 v = *(const float4*)(in + (size_t)(tk + r) * N + tn + coff);
        tile[r][coff + 0] = f2bf(v.x);
        tile[r][coff + 1] = f2bf(v.y);
        tile[r][coff + 2] = f2bf(v.z);
        tile[r][coff + 3] = f2bf(v.w);
    }
    __syncthreads();
    for (int c = tid; c < 512; c += 256) {
        int rn = c >> 3, off = (c & 7) * 8;
        unsigned short tmp[8];
        #pragma unroll
        for (int j = 0; j < 8; j++) tmp[j] = tile[off + j][rn];
        *(uint4*)(out + (size_t)(tn + rn) * K + tk + off) = *(uint4*)tmp;
    }
}

__global__ __launch_bounds__(256) void fused_transpose(
    const float* __restrict__ qkvw, const float* __restrict__ projw,
    const float* __restrict__ fc1w, const float* __restrict__ fc2w,
    unsigned short* __restrict__ qkv_wT, unsigned short* __restrict__ proj_wT,
    unsigned short* __restrict__ fc1_wT, unsigned short* __restrict__ fc2_wT) {
    __shared__ unsigned short tile[64][65];
    int id = blockIdx.x, tid = threadIdx.x;
    if (id < 768) {
        tp_tile(qkvw, qkv_wT, 1024, 3072, (id % 48) * 64, (id / 48) * 64, tid, tile);
    } else if (id < 1024) {
        id -= 768;
        tp_tile(projw, proj_wT, 1024, 1024, (id % 16) * 64, (id / 16) * 64, tid, tile);
    } else if (id < 2048) {
        id -= 1024;
        tp_tile(fc1w, fc1_wT, 1024, 4096, (id % 64) * 64, (id / 64) * 64, tid, tile);
    } else {
        id -= 2048;
        tp_tile(fc2w, fc2_wT, 4096, 1024, (id % 16) * 64, (id / 16) * 64, tid, tile);
    }
}

// ---------------------------------------------------------------------------
// Per-head V transpose: v_buf (bh, t, d) -> vT_buf (bh, d, t), bf16.
// ---------------------------------------------------------------------------
__global__ __launch_bounds__(256) void transpose_v(const unsigned short* __restrict__ in,
                                                   unsigned short* __restrict__ out) {
    __shared__ unsigned short tile[64][65];
    int t0 = blockIdx.x * 64;
    int bh = blockIdx.y;
    const unsigned short* ip = in + (size_t)bh * SEQ * HD;
    unsigned short* op = out + (size_t)bh * HD * SEQ;
    int tid = threadIdx.x;
    for (int c = tid; c < 512; c += 256) {
        int r = c >> 3, off = (c & 7) * 8;
        *(uint4*)&tile[r][off] = *(const uint4*)(ip + (size_t)(t0 + r) * HD + off);
    }
    __syncthreads();
    for (int c = tid; c < 512; c += 256) {
        int rn = c >> 3, off = (c & 7) * 8;
        unsigned short tmp[8];
        #pragma unroll
        for (int j = 0; j < 8; j++) tmp[j] = tile[off + j][rn];
        *(uint4*)(op + (size_t)rn * SEQ + t0 + off) = *(uint4*)tmp;
    }
}

// ---------------------------------------------------------------------------
// LayerNorm: f32 input, f32 w/b, bf16 output. One block per row (DIMC=1024).
// ---------------------------------------------------------------------------
__global__ __launch_bounds__(256) void ln_kernel(const float* __restrict__ inp,
                                                 const float* __restrict__ w,
                                                 const float* __restrict__ b,
                                                 unsigned short* __restrict__ out) {
    int row = blockIdx.x;
    int tid = threadIdx.x;
    int base = tid * 4;
    float4 v = *(const float4*)(inp + (size_t)row * DIMC + base);
    float x[4] = {v.x, v.y, v.z, v.w};
    float s1 = x[0] + x[1] + x[2] + x[3];
    float s2 = x[0]*x[0] + x[1]*x[1] + x[2]*x[2] + x[3]*x[3];
    #pragma unroll
    for (int off = 32; off > 0; off >>= 1) {
        s1 += __shfl_xor(s1, off);
        s2 += __shfl_xor(s2, off);
    }
    __shared__ float red[8];
    int wv = tid >> 6;
    if ((tid & 63) == 0) { red[wv] = s1; red[4 + wv] = s2; }
    __syncthreads();
    s1 = red[0] + red[1] + red[2] + red[3];
    s2 = red[4] + red[5] + red[6] + red[7];
    float mean = s1 * (1.0f / DIMC);
    float var  = s2 * (1.0f / DIMC) - mean * mean;
    float rstd = rsqrtf(var + 1e-5f);
    float4 wv4 = *(const float4*)(w + base);
    float4 bv4 = *(const float4*)(b + base);
    ushort4 o;
    o.x = f2bf((x[0] - mean) * rstd * wv4.x + bv4.x);
    o.y = f2bf((x[1] - mean) * rstd * wv4.y + bv4.y);
    o.z = f2bf((x[2] - mean) * rstd * wv4.z + bv4.z);
    o.w = f2bf((x[3] - mean) * rstd * wv4.w + bv4.w);
    *(ushort4*)(out + (size_t)row * DIMC + base) = o;
}

// ---------------------------------------------------------------------------
// bf16 MFMA GEMM: C(M x N) = A(M x K) @ BT(N x K)^T.
// Tile TM x 128, 4 waves (2x2), XOR-swizzled LDS, global_load_lds staging.
//
// Round 4: T3-minimum pipeline — DOUBLE-BUFFERED LDS + counted vmcnt + raw
// s_barrier. Stage tile t+1 into buf^1 BEFORE computing tile t; wait only
// vmcnt(N_LD) (t's own loads), never 0 in-loop, so next-tile loads stay in
// flight across both barriers. R3 evidence for regime: K=1024 -> 16 lockstep
// iters, MfmaUtil 17 / VALU 33 / HBM 12 / occ 20 -> latency-exposed barrier
// drain, not hidden by TLP. LDS 64KB (TM=128) -> 2 blocks/CU: intentional —
// intra-block ILP replaces TLP.
// ---------------------------------------------------------------------------
enum { EP_QKV = 0, EP_PROJ = 1, EP_FC1 = 2, EP_FC2 = 3 };

template <int MODE, int N, int K, int TM, int BK>
__global__ __launch_bounds__(256) void gemm_kernel(
    const unsigned short* __restrict__ A,
    const unsigned short* __restrict__ BT,
    const float* __restrict__ bias,
    const float* __restrict__ res,      // fp32 residual (PROJ: x, FC2: x1)
    void* __restrict__ out0,
    unsigned short* __restrict__ q_buf,
    unsigned short* __restrict__ k_buf,
    unsigned short* __restrict__ v_buf) {
    constexpr int MI = TM / 32;
    constexpr int CPR = BK / 8;
    constexpr int NT = K / BK;
    constexpr int N_LD = (TM * BK + 128 * BK) / 2048;  // gload_lds per thread per tile
    static_assert(N_LD == 8 || N_LD == 6, "vmcnt literal");
    __shared__ __align__(16) unsigned short As[2 * TM * BK];
    __shared__ __align__(16) unsigned short Bs[2 * 128 * BK];
    const int tid = threadIdx.x;
    const int m0 = blockIdx.y * TM;
    const int n0 = blockIdx.x * 128;
    const int wave = tid >> 6, lane = tid & 63;
    const int wm = wave >> 1, wn = wave & 1;
    const int quad = lane >> 4, l16 = lane & 15;
    const int swz = l16 & (CPR - 1);

    f32x4 acc[MI][4] = {};

    auto stage = [&](int t, int b) {
        const size_t kk = (size_t)t * BK;
        #pragma unroll
        for (int it = 0; it < TM * BK / 2048; ++it) {
            int c = tid + 256 * it;
            int row = c / CPR, jj = c % CPR;
            int col8 = (jj ^ (row & (CPR - 1))) * 8;
            GLOAD_LDS(A + (size_t)(m0 + row) * K + kk + col8,
                      As + (size_t)b * TM * BK + (size_t)c * 8);
        }
        #pragma unroll
        for (int it = 0; it < 128 * BK / 2048; ++it) {
            int c = tid + 256 * it;
            int row = c / CPR, jj = c % CPR;
            int col8 = (jj ^ (row & (CPR - 1))) * 8;
            GLOAD_LDS(BT + (size_t)(n0 + row) * K + kk + col8,
                      Bs + (size_t)b * 128 * BK + (size_t)c * 8);
        }
    };

    stage(0, 0);
    for (int t = 0; t < NT; ++t) {
        const int cur = t & 1;
        if (t + 1 < NT) {
            stage(t + 1, cur ^ 1);
            // wait tile t's N_LD loads; leave tile t+1's in flight (never 0)
            if constexpr (N_LD == 8) asm volatile("s_waitcnt vmcnt(8)" ::: "memory");
            else                     asm volatile("s_waitcnt vmcnt(6)" ::: "memory");
        } else {
            asm volatile("s_waitcnt vmcnt(0)" ::: "memory");
        }
        __builtin_amdgcn_s_barrier();

        const unsigned short* Asb = As + (size_t)cur * TM * BK;
        const unsigned short* Bsb = Bs + (size_t)cur * 128 * BK;
        #pragma unroll
        for (int kk2 = 0; kk2 < BK / 32; ++kk2) {
            bf16x8 af[MI], bfv[4];
            #pragma unroll
            for (int i = 0; i < MI; i++) {
                int row = 16 * MI * wm + 16 * i + l16;
                int sj = (4 * kk2 + quad) ^ swz;
                af[i] = *(const bf16x8*)&Asb[row * BK + sj * 8];
            }
            #pragma unroll
            for (int j = 0; j < 4; j++) {
                int row = 64 * wn + 16 * j + l16;
                int sj = (4 * kk2 + quad) ^ swz;
                bfv[j] = *(const bf16x8*)&Bsb[row * BK + sj * 8];
            }
            #pragma unroll
            for (int i = 0; i < MI; i++)
                #pragma unroll
                for (int j = 0; j < 4; j++)
                    acc[i][j] = __builtin_amdgcn_mfma_f32_16x16x32_bf16(af[i], bfv[j], acc[i][j], 0, 0, 0);
        }
        // all this wave's ds_reads complete (results consumed), then barrier so
        // next iter's stage into buf[cur] can't race other waves' reads.
        asm volatile("s_waitcnt lgkmcnt(0)" ::: "memory");
        __builtin_amdgcn_s_barrier();
    }

    #pragma unroll
    for (int i = 0; i < MI; i++) {
        #pragma unroll
        for (int j = 0; j < 4; j++) {
            int nl = n0 + 64 * wn + 16 * j + l16;
            float bval = 0.0f;
            if (MODE != EP_QKV) bval = bias[nl];
            #pragma unroll
            for (int r = 0; r < 4; r++) {
                int ml = m0 + 16 * MI * wm + 16 * i + quad * 4 + r;
                float v = acc[i][j][r];
                if (MODE == EP_QKV) {
                    int which = nl >> 10, rem = nl & 1023;
                    int hh = rem >> 6, d = rem & 63;
                    int bb = ml >> 11, t2 = ml & 2047;
                    int bh = bb * HEADS + hh;
                    // q pre-scale = (1/8) * log2(e) so softmax is a bare v_exp_f32 (2^x)
                    if (which == 0)      q_buf[((size_t)bh * SEQ + t2) * HD + d] = f2bf(v * 0.18033688011112042f);
                    else if (which == 1) k_buf[((size_t)bh * SEQ + t2) * HD + d] = f2bf(v);
                    else                 v_buf[((size_t)bh * SEQ + t2) * HD + d] = f2bf(v);
                } else if (MODE == EP_PROJ) {
                    float* x1 = (float*)out0;
                    x1[(size_t)ml * DIMC + nl] = res[(size_t)ml * DIMC + nl] + v + bval;
                } else if (MODE == EP_FC1) {
                    float g = v + bval;
                    float u = 1.5957691216f * (g + 0.044715f * g * g * g);
                    float gv = g / (1.0f + __expf(-u));
                    ((unsigned short*)out0)[(size_t)ml * HIDDENC + nl] = f2bf(gv);
                } else {
                    ((float*)out0)[(size_t)ml * DIMC + nl] =
                        res[(size_t)ml * DIMC + nl] + v + bval;
                }
            }
        }
    }
}

// ---------------------------------------------------------------------------
// Split-K flash attention partials. No online max (|s|<~7 after LN).
// Key-padding semantics MUST match the reference's fp32 "+(-1e9)":
// all masked scores collapse to the SAME value (uniform softmax when a row's
// visible keys are all masked). So masked keys get a CONSTANT weight 1e-13:
// normal rows see <=1e-7 relative perturbation; all-masked rows get
// exactly-uniform weights, matching ref. Partials combine by plain summation.
//
// Swapped QK^T (S^T = mfma(K,Q)): lane holds one q (=l16) and 4 consecutive
// keys -> P-store = 2x cvt_pk + 1x ds_write_b64 per ct; PV A-read is a
// contiguous ds_read_b128 from the XOR-swizzled row-major Ps[q][key].
// O_part store staged through LDS -> 2x dwordx4/lane full-line writes.
// XCD-aware 1D swizzle keeps all 80 slots of one (b,h) on one XCD.
// ---------------------------------------------------------------------------
#define KP 72
#define PMASK 1e-13f
__global__ __launch_bounds__(256, 6) void attn_partial(
    const unsigned short* __restrict__ q_buf,
    const unsigned short* __restrict__ k_buf,
    const unsigned short* __restrict__ vT_buf,
    const int* __restrict__ mask,
    unsigned short* __restrict__ opart0,   // d_out scratch (bh 0..24)
    unsigned short* __restrict__ opart1,   // x1 scratch (bh 25..31)
    float* __restrict__ l_part) {
    __shared__ __align__(16) unsigned short Ks[64 * KP];
    __shared__ __align__(16) unsigned short Vs[64 * KP];
    __shared__ __align__(16) unsigned short Ps[4 * 16 * 64];  // per-wave swizzled P[q][key]; O-stage after loop
    __shared__ __align__(16) float Msf[64];

    // XCD-aware decode: consecutive blockIdx round-robin XCDs; keep all 80
    // slots of one bh on one XCD. Bijective on [0,2560).
    const int j = blockIdx.x;
    const int xcd = j & 7;
    const int t = j >> 3;            // 0..319
    const int slot = t % NSLOT;
    const int bg = t / NSLOT;        // 0..3
    const int bh = bg * 8 + xcd;     // 0..31
    const int bb = bh >> 4, h = bh & 15;

    // slot -> (qt, chunk)
    int s = slot, qt, c;
    if (s < 8)       { qt = s;              c = 0;     }
    else if (s < 24) { s -= 8;  qt = 8  + (s >> 1); c = s & 1; }
    else if (s < 48) { s -= 24; qt = 16 + s / 3;    c = s % 3; }
    else             { s -= 48; qt = 24 + (s >> 2); c = s & 3; }
    const int kt0 = c * 8;
    const int kt1 = min(kt0 + 8, qt + 1);

    const int tid = threadIdx.x, wave = tid >> 6, lane = tid & 63;
    const int quad = lane >> 4, l16 = lane & 15;
    const unsigned short* qp = q_buf + (size_t)bh * SEQ * HD;
    const unsigned short* kp = k_buf + (size_t)bh * SEQ * HD;
    const unsigned short* vp = vT_buf + (size_t)bh * HD * SEQ;
    const int* mrow_ptr = mask + bb * SEQ;

    const int qrow = qt * 64 + wave * 16 + l16;   // this lane's q (global)
    bf16x8 qf[2];
    qf[0] = *(const bf16x8*)(qp + (size_t)qrow * HD + 8 * quad);
    qf[1] = *(const bf16x8*)(qp + (size_t)qrow * HD + 32 + 8 * quad);

    f32x4 o[4] = {};
    float lsum = 0.0f;

    const int r0 = tid >> 3, c0 = (tid & 7) * 8;
    const int r1 = r0 + 32;

    // per-wave swizzled Ps addressing (bytes): row = q = l16, 128 B rows
    char* psb = (char*)Ps + wave * 2048 + l16 * 128;
    const int swz = (l16 & 7) << 4;

    // prefetch first tile of the chunk; Msf holds 1.0 = masked, 0.0 = visible
    uint4 pk0, pk1, pv0, pv1; float pmv = 0.0f;
    pk0 = *(const uint4*)(kp + (size_t)(kt0 * 64 + r0) * HD + c0);
    pk1 = *(const uint4*)(kp + (size_t)(kt0 * 64 + r1) * HD + c0);
    pv0 = *(const uint4*)(vp + (size_t)r0 * SEQ + kt0 * 64 + c0);
    pv1 = *(const uint4*)(vp + (size_t)r1 * SEQ + kt0 * 64 + c0);
    if (tid < 64) pmv = mrow_ptr[kt0 * 64 + tid] ? 1.0f : 0.0f;

    for (int kt = kt0; kt < kt1; kt++) {
        __syncthreads();
        *(uint4*)&Ks[r0 * KP + c0] = pk0;
        *(uint4*)&Ks[r1 * KP + c0] = pk1;
        *(uint4*)&Vs[r0 * KP + c0] = pv0;
        *(uint4*)&Vs[r1 * KP + c0] = pv1;
        if (tid < 64) Msf[tid] = pmv;
        if (kt + 1 < kt1) {
            pk0 = *(const uint4*)(kp + (size_t)((kt + 1) * 64 + r0) * HD + c0);
            pk1 = *(const uint4*)(kp + (size_t)((kt + 1) * 64 + r1) * HD + c0);
            pv0 = *(const uint4*)(vp + (size_t)r0 * SEQ + (kt + 1) * 64 + c0);
            pv1 = *(const uint4*)(vp + (size_t)r1 * SEQ + (kt + 1) * 64 + c0);
            if (tid < 64) pmv = mrow_ptr[(kt + 1) * 64 + tid] ? 1.0f : 0.0f;
        }
        __syncthreads();

        // S^T = K @ Q^T : sc[ct][r] = S[key=16ct+4quad+r][q=l16]
        f32x4 sc[4];
        __builtin_amdgcn_s_setprio(1);
        #pragma unroll
        for (int ct = 0; ct < 4; ct++) {
            f32x4 z = {};
            #pragma unroll
            for (int ss = 0; ss < 2; ss++) {
                bf16x8 kf = *(const bf16x8*)&Ks[(16 * ct + l16) * KP + 32 * ss + 8 * quad];
                z = __builtin_amdgcn_mfma_f32_16x16x32_bf16(kf, qf[ss], z, 0, 0, 0);
            }
            sc[ct] = z;
        }
        __builtin_amdgcn_s_setprio(0);

        const bool diag = (kt == qt);
        #pragma unroll
        for (int ct = 0; ct < 4; ct++) {
            float4 mq = *(const float4*)&Msf[16 * ct + 4 * quad];
            float mfs[4] = {mq.x, mq.y, mq.z, mq.w};
            const int kg0 = kt * 64 + 16 * ct + 4 * quad;
            float pv4[4];
            #pragma unroll
            for (int r = 0; r < 4; r++) {
                float p = (mfs[r] != 0.0f) ? PMASK : exp2_fast(sc[ct][r]);
                if (diag && (kg0 + r) > qrow) p = 0.0f;
                lsum += p;
                pv4[r] = p;
            }
            uint2 w;
            w.x = cvt_pk_bf16(pv4[0], pv4[1]);
            w.y = cvt_pk_bf16(pv4[2], pv4[3]);
            // P[q=l16][key=16ct+4quad .. +3]: logical byte quad*8+ct*32, swizzled
            *(uint2*)(psb + ((quad * 8 + ct * 32) ^ swz)) = w;
        }
        asm volatile("" ::: "memory");   // order punned LDS write -> read

        __builtin_amdgcn_s_setprio(1);
        #pragma unroll
        for (int ss = 0; ss < 2; ss++) {
            bf16x8 pf = *(const bf16x8*)(psb + ((ss * 64 + quad * 16) ^ swz));
            #pragma unroll
            for (int dt = 0; dt < 4; dt++) {
                bf16x8 vf = *(const bf16x8*)&Vs[(16 * dt + l16) * KP + 32 * ss + 8 * quad];
                o[dt] = __builtin_amdgcn_mfma_f32_16x16x32_bf16(pf, vf, o[dt], 0, 0, 0);
            }
        }
        __builtin_amdgcn_s_setprio(0);
    }

    // row-sum for q=l16 lives replicated across quads: butterfly over quads
    lsum += __shfl_xor(lsum, 16);
    lsum += __shfl_xor(lsum, 32);
    if (lane < 16)
        l_part[((size_t)bh * NSLOT + slot) * 64 + wave * 16 + lane] = lsum;

    // O store: stage the wave's 16x64 subtile in its private Ps region (dead
    // now), then write 2x dwordx4 per lane -> full-line coalesced HBM writes.
    unsigned short* Ls = Ps + wave * 1024;   // 16 rows x 64 cols bf16 = 2 KB
    #pragma unroll
    for (int dt = 0; dt < 4; dt++)
        #pragma unroll
        for (int r = 0; r < 4; r++)
            Ls[(quad * 4 + r) * 64 + 16 * dt + l16] = f2bf(o[dt][r]);
    asm volatile("" ::: "memory");           // order punned LDS write -> read
    unsigned short* ob = opart_base(opart0, opart1, bh)
                         + (size_t)slot * 4096 + wave * 1024;
    uint4 w0 = *(const uint4*)&Ls[lane * 8];
    uint4 w1 = *(const uint4*)&Ls[512 + lane * 8];
    *(uint4*)(ob + lane * 8) = w0;
    *(uint4*)(ob + 512 + lane * 8) = w1;
}

// ---------------------------------------------------------------------------
// Combine partials: attn_o[bh][t][d] = (sum_c O_c) / (sum_c l_c), bf16.
// One block per (qt, h, b).
// ---------------------------------------------------------------------------
__global__ __launch_bounds__(256) void attn_combine(
    const unsigned short* __restrict__ opart0,
    const unsigned short* __restrict__ opart1,
    const float* __restrict__ l_part,
    unsigned short* __restrict__ attn_o) {
    const int qt = blockIdx.x, h = blockIdx.y, bb = blockIdx.z;
    const int bh = bb * HEADS + h;
    const int g = qt >> 3;
    const int n = g + 1;
    const int baseB[4] = {0, 8, 24, 48};
    const int slot0 = baseB[g] + (qt - 8 * g) * n;
    const int tid = threadIdx.x;
    __shared__ float linv[64];
    if (tid < 64) {
        float acc = 0.0f;
        for (int cc = 0; cc < n; cc++)
            acc += l_part[((size_t)bh * NSLOT + slot0 + cc) * 64 + tid];
        linv[tid] = 1.0f / acc;
    }
    __syncthreads();
    const unsigned short* ob = opart_base((unsigned short*)opart0, (unsigned short*)opart1, bh)
                               + (size_t)slot0 * 4096;
    #pragma unroll
    for (int i = 0; i < 16; i++) {
        int idx = i * 256 + tid;          // 0..4095
        int row = idx >> 6, d = idx & 63;
        float acc = 0.0f;
        for (int cc = 0; cc < n; cc++)
            acc += bf2f(ob[(size_t)cc * 4096 + idx]);
        attn_o[((size_t)(bb * SEQ + qt * 64 + row)) * DIMC + h * HD + d] =
            f2bf(acc * linv[row]);
    }
}

// ---------------------------------------------------------------------------
extern "C" void kernel_launch(void* const* d_in, const int* in_sizes, int n_in,
                              void* d_out, int out_size, void* d_ws, size_t ws_size,
                              hipStream_t stream) {
    const float* x     = (const float*)d_in[0];
    const int*   mask  = (const int*)d_in[1];
    const float* ln1w  = (const float*)d_in[2];
    const float* ln1b  = (const float*)d_in[3];
    const float* qkvw  = (const float*)d_in[4];
    const float* projw = (const float*)d_in[5];
    const float* projb = (const float*)d_in[6];
    const float* ln2w  = (const float*)d_in[7];
    const float* ln2b  = (const float*)d_in[8];
    const float* fc1w  = (const float*)d_in[9];
    const float* fc1b  = (const float*)d_in[10];
    const float* fc2w  = (const float*)d_in[11];
    const float* fc2b  = (const float*)d_in[12];

    // Workspace (80 MB, lifetime reuse):
    //  [0,6M)    qkv_wT (dead after QKV gemm) | l_part [0,640K) during attn
    //  [6,8M)    proj_wT
    //  [8,16M)   fc1_wT
    //  [16,24M)  fc2_wT
    //  [24,32M)  ln_buf (ln1, later ln2)
    //  [32,40M)  q_buf   | h_buf [32,64M) at FC1
    //  [40,48M)  k_buf
    //  [48,56M)  v_buf -> attn_o (combine output)
    //  [56,64M)  vT_buf
    //  [64,80M)  O_part overflow (bh 25..31, 4.6M) during attn; x1 fp32 after
    // d_out (16.8M fp32 out): O_part scratch (bh 0..24) until FC2 overwrites.
    char* base = (char*)d_ws;
    unsigned short* qkv_wT  = (unsigned short*)(base);
    float*          l_part  = (float*)(base);                              // alias, post-QKV
    unsigned short* proj_wT = (unsigned short*)(base + (size_t)6  * 1024 * 1024);
    unsigned short* fc1_wT  = (unsigned short*)(base + (size_t)8  * 1024 * 1024);
    unsigned short* fc2_wT  = (unsigned short*)(base + (size_t)16 * 1024 * 1024);
    unsigned short* ln_buf  = (unsigned short*)(base + (size_t)24 * 1024 * 1024);
    unsigned short* q_buf   = (unsigned short*)(base + (size_t)32 * 1024 * 1024);
    unsigned short* k_buf   = (unsigned short*)(base + (size_t)40 * 1024 * 1024);
    unsigned short* v_buf   = (unsigned short*)(base + (size_t)48 * 1024 * 1024);
    unsigned short* attn_o  = (unsigned short*)(base + (size_t)48 * 1024 * 1024); // alias v_buf
    unsigned short* vT_buf  = (unsigned short*)(base + (size_t)56 * 1024 * 1024);
    unsigned short* h_buf   = (unsigned short*)(base + (size_t)32 * 1024 * 1024); // reuse
    float*          x1      = (float*)(base + (size_t)64 * 1024 * 1024);
    unsigned short* opart1  = (unsigned short*)(base + (size_t)64 * 1024 * 1024); // alias x1
    unsigned short* opart0  = (unsigned short*)d_out;                             // scratch until FC2

    // 1. all 4 weight transposes in one launch
    fused_transpose<<<3072, 256, 0, stream>>>(qkvw, projw, fc1w, fc2w,
                                              qkv_wT, proj_wT, fc1_wT, fc2_wT);

    // 2. LN1 (fp32 x -> bf16)
    ln_kernel<<<MTOK, 256, 0, stream>>>(x, ln1w, ln1b, ln_buf);

    // 3. QKV GEMM -> q (pre-scaled by log2e/8), k, v (all [bh][t][d])
    gemm_kernel<EP_QKV, 3072, 1024, 128, 64><<<dim3(24, 32), 256, 0, stream>>>(
        ln_buf, qkv_wT, nullptr, nullptr, nullptr, q_buf, k_buf, v_buf);

    // 4. V transpose -> vT [bh][d][t]
    transpose_v<<<dim3(SEQ / 64, BATCH * HEADS), 256, 0, stream>>>(v_buf, vT_buf);

    // 5a. split-K attention partials (2560 blocks, XCD-swizzled 1D grid)
    attn_partial<<<NSLOT * HEADS * BATCH, 256, 0, stream>>>(
        q_buf, k_buf, vT_buf, mask, opart0, opart1, l_part);

    // 5b. combine -> attn_o (aliases v_buf, dead now)
    attn_combine<<<dim3(SEQ / 64, HEADS, BATCH), 256, 0, stream>>>(
        opart0, opart1, l_part, attn_o);

    // 6. proj GEMM + residual(x fp32) -> x1 (fp32; O_part overflow dead now)
    gemm_kernel<EP_PROJ, 1024, 1024, 64, 64><<<dim3(8, 64), 256, 0, stream>>>(
        attn_o, proj_wT, projb, x, x1, nullptr, nullptr, nullptr);

    // 7. LN2 (fp32 x1 -> bf16)
    ln_kernel<<<MTOK, 256, 0, stream>>>(x1, ln2w, ln2b, ln_buf);

    // 8. FC1 + GELU -> h_buf (bf16)
    gemm_kernel<EP_FC1, 4096, 1024, 128, 64><<<dim3(32, 32), 256, 0, stream>>>(
        ln_buf, fc1_wT, fc1b, nullptr, h_buf, nullptr, nullptr, nullptr);

    // 9. FC2 + residual(x1) -> d_out (fp32; overwrites O_part scratch fully)
    gemm_kernel<EP_FC2, 1024, 4096, 64, 64><<<dim3(8, 64), 256, 0, stream>>>(
        h_buf, fc2_wT, fc2b, x1, d_out, nullptr, nullptr, nullptr);
}

// Round 5
// 376.947 us; speedup vs baseline: 1.0696x; 1.0337x over previous
//
#include <hip/hip_runtime.h>
#include <stdint.h>

#define DIMC 1024
#define HEADS 16
#define HD 64
#define HIDDENC 4096
#define BATCH 2
#define SEQ 2048
#define MTOK (BATCH*SEQ)
#define NSLOT 80            // split-K chunk slots per (b,h): 8*1+8*2+8*3+8*4
#define BH_ELEMS (NSLOT*64*64)   // bf16 elems of O_part per bh = 327680

typedef __bf16 bf16x8 __attribute__((ext_vector_type(8)));
typedef float f32x4 __attribute__((ext_vector_type(4)));

__device__ __forceinline__ float bf2f(unsigned short u) {
    union { unsigned int u; float f; } v; v.u = ((unsigned int)u) << 16; return v.f;
}
__device__ __forceinline__ unsigned short f2bf(float f) {
    union { float f; unsigned int u; } v; v.f = f;
    unsigned int r = v.u + 0x7fffu + ((v.u >> 16) & 1u);
    return (unsigned short)(r >> 16);
}
// pack 2 f32 -> 2 bf16 (RNE), src0 -> low half (T12 recipe, guide-verified)
__device__ __forceinline__ unsigned int cvt_pk_bf16(float lo, float hi) {
    unsigned int r;
    asm("v_cvt_pk_bf16_f32 %0, %1, %2" : "=v"(r) : "v"(lo), "v"(hi));
    return r;
}
// 2^x (log2e is pre-folded into the Q scale)
__device__ __forceinline__ float exp2_fast(float x) {
#if __has_builtin(__builtin_amdgcn_exp2f)
    return __builtin_amdgcn_exp2f(x);
#else
    float r;
    asm("v_exp_f32 %0, %1" : "=v"(r) : "v"(x));
    return r;
#endif
}

#define GLOAD_LDS(g, l) \
    __builtin_amdgcn_global_load_lds( \
        (const __attribute__((address_space(1))) void*)(g), \
        (__attribute__((address_space(3))) void*)(l), 16, 0, 0)

// O_part is split across d_out (first 25 bh) and the x1 region (last 7 bh).
__device__ __forceinline__ unsigned short* opart_base(
    unsigned short* o0, unsigned short* o1, int bh) {
    return (bh < 25) ? (o0 + (size_t)bh * BH_ELEMS)
                     : (o1 + (size_t)(bh - 25) * BH_ELEMS);
}

// ---------------------------------------------------------------------------
// Fused weight transposes: fp32 (K x N) -> bf16 (N x K) for all 4 weights.
// ---------------------------------------------------------------------------
__device__ __forceinline__ void tp_tile(const float* __restrict__ in,
                                        unsigned short* __restrict__ out,
                                        int K, int N, int tn, int tk, int tid,
                                        unsigned short (*tile)[65]) {
    for (int c = tid; c < 1024; c += 256) {
        int r = c >> 4, coff = (c & 15) * 4;
        float4 v = *(const float4*)(in + (size_t)(tk + r) * N + tn + coff);
        tile[r][coff + 0] = f2bf(v.x);
        tile[r][coff + 1] = f2bf(v.y);
        tile[r][coff + 2] = f2bf(v.z);
        tile[r][coff + 3] = f2bf(v.w);
    }
    __syncthreads();
    for (int c = tid; c < 512; c += 256) {
        int rn = c >> 3, off = (c & 7) * 8;
        unsigned short tmp[8];
        #pragma unroll
        for (int j = 0; j < 8; j++) tmp[j] = tile[off + j][rn];
        *(uint4*)(out + (size_t)(tn + rn) * K + tk + off) = *(uint4*)tmp;
    }
}

__global__ __launch_bounds__(256) void fused_transpose(
    const float* __restrict__ qkvw, const float* __restrict__ projw,
    const float* __restrict__ fc1w, const float* __restrict__ fc2w,
    unsigned short* __restrict__ qkv_wT, unsigned short* __restrict__ proj_wT,
    unsigned short* __restrict__ fc1_wT, unsigned short* __restrict__ fc2_wT) {
    __shared__ unsigned short tile[64][65];
    int id = blockIdx.x, tid = threadIdx.x;
    if (id < 768) {
        tp_tile(qkvw, qkv_wT, 1024, 3072, (id % 48) * 64, (id / 48) * 64, tid, tile);
    } else if (id < 1024) {
        id -= 768;
        tp_tile(projw, proj_wT, 1024, 1024, (id % 16) * 64, (id / 16) * 64, tid, tile);
    } else if (id < 2048) {
        id -= 1024;
        tp_tile(fc1w, fc1_wT, 1024, 4096, (id % 64) * 64, (id / 64) * 64, tid, tile);
    } else {
        id -= 2048;
        tp_tile(fc2w, fc2_wT, 4096, 1024, (id % 16) * 64, (id / 16) * 64, tid, tile);
    }
}

// ---------------------------------------------------------------------------
// Per-head V transpose: v_buf (bh, t, d) -> vT_buf (bh, d, t), bf16.
// ---------------------------------------------------------------------------
__global__ __launch_bounds__(256) void transpose_v(const unsigned short* __restrict__ in,
                                                   unsigned short* __restrict__ out) {
    __shared__ unsigned short tile[64][65];
    int t0 = blockIdx.x * 64;
    int bh = blockIdx.y;
    const unsigned short* ip = in + (size_t)bh * SEQ * HD;
    unsigned short* op = out + (size_t)bh * HD * SEQ;
    int tid = threadIdx.x;
    for (int c = tid; c < 512; c += 256) {
        int r = c >> 3, off = (c & 7) * 8;
        *(uint4*)&tile[r][off] = *(const uint4*)(ip + (size_t)(t0 + r) * HD + off);
    }
    __syncthreads();
    for (int c = tid; c < 512; c += 256) {
        int rn = c >> 3, off = (c & 7) * 8;
        unsigned short tmp[8];
        #pragma unroll
        for (int j = 0; j < 8; j++) tmp[j] = tile[off + j][rn];
        *(uint4*)(op + (size_t)rn * SEQ + t0 + off) = *(uint4*)tmp;
    }
}

// ---------------------------------------------------------------------------
// LayerNorm: f32 input, f32 w/b, bf16 output. One block per row (DIMC=1024).
// ---------------------------------------------------------------------------
__global__ __launch_bounds__(256) void ln_kernel(const float* __restrict__ inp,
                                                 const float* __restrict__ w,
                                                 const float* __restrict__ b,
                                                 unsigned short* __restrict__ out) {
    int row = blockIdx.x;
    int tid = threadIdx.x;
    int base = tid * 4;
    float4 v = *(const float4*)(inp + (size_t)row * DIMC + base);
    float x[4] = {v.x, v.y, v.z, v.w};
    float s1 = x[0] + x[1] + x[2] + x[3];
    float s2 = x[0]*x[0] + x[1]*x[1] + x[2]*x[2] + x[3]*x[3];
    #pragma unroll
    for (int off = 32; off > 0; off >>= 1) {
        s1 += __shfl_xor(s1, off);
        s2 += __shfl_xor(s2, off);
    }
    __shared__ float red[8];
    int wv = tid >> 6;
    if ((tid & 63) == 0) { red[wv] = s1; red[4 + wv] = s2; }
    __syncthreads();
    s1 = red[0] + red[1] + red[2] + red[3];
    s2 = red[4] + red[5] + red[6] + red[7];
    float mean = s1 * (1.0f / DIMC);
    float var  = s2 * (1.0f / DIMC) - mean * mean;
    float rstd = rsqrtf(var + 1e-5f);
    float4 wv4 = *(const float4*)(w + base);
    float4 bv4 = *(const float4*)(b + base);
    ushort4 o;
    o.x = f2bf((x[0] - mean) * rstd * wv4.x + bv4.x);
    o.y = f2bf((x[1] - mean) * rstd * wv4.y + bv4.y);
    o.z = f2bf((x[2] - mean) * rstd * wv4.z + bv4.z);
    o.w = f2bf((x[3] - mean) * rstd * wv4.w + bv4.w);
    *(ushort4*)(out + (size_t)row * DIMC + base) = o;
}

// ---------------------------------------------------------------------------
// bf16 MFMA GEMM: C(M x N) = A(M x K) @ BT(N x K)^T.
// Tile TM x TN, 4 waves (2x2), XOR-swizzled LDS, global_load_lds staging,
// double-buffered with counted vmcnt (R4).
//
// Round 5 (counter-driven):
//  - 1D XCD-swizzled grid (MG=4 m-groups x NG=2 n-groups): R4 evidence — FC2
//    FETCH 143MB vs 59 ideal because dim3(8,64) put each m-tile's 8 n-blocks
//    on 8 different XCDs (A-dup=8, 268MB logical). Rectangle partition cuts
//    FC2 to ~100MB, FC1 ~50, QKV ~42. n-fastest within XCD so co-resident
//    blocks share A-panels (per-K-step working set ~200KB, L2-resident).
//  - TN=64 for PROJ/FC2: grid 512 -> 1024 blocks (2 -> 4 blocks/CU resident;
//    R4 occupancy 19% was grid-limited), LDS 32KB, N_LD=4.
// ---------------------------------------------------------------------------
enum { EP_QKV = 0, EP_PROJ = 1, EP_FC1 = 2, EP_FC2 = 3 };

template <int MODE, int N, int K, int TM, int TN, int BK>
__global__ __launch_bounds__(256) void gemm_kernel(
    const unsigned short* __restrict__ A,
    const unsigned short* __restrict__ BT,
    const float* __restrict__ bias,
    const float* __restrict__ res,      // fp32 residual (PROJ: x, FC2: x1)
    void* __restrict__ out0,
    unsigned short* __restrict__ q_buf,
    unsigned short* __restrict__ k_buf,
    unsigned short* __restrict__ v_buf) {
    constexpr int MI = TM / 32;          // m-fragments per wave (2 waves in m)
    constexpr int NJ = TN / 32;          // n-fragments per wave (2 waves in n)
    constexpr int CPR = BK / 8;
    constexpr int NT = K / BK;
    constexpr int N_LD = (TM + TN) * BK / 2048;  // gload_lds per thread per tile
    static_assert(N_LD == 8 || N_LD == 4, "vmcnt literal");
    constexpr int NX = N / TN;
    constexpr int NY = MTOK / TM;
    constexpr int MG = 4, NG = 2;        // XCD rectangle partition
    constexpr int NXG = NX / NG, NYG = NY / MG;
    static_assert(NX % NG == 0 && NY % MG == 0, "partition divisibility");

    __shared__ __align__(16) unsigned short As[2 * TM * BK];
    __shared__ __align__(16) unsigned short Bs[2 * TN * BK];
    const int tid = threadIdx.x;

    // XCD-aware decode (1D grid, consecutive ids round-robin XCDs)
    const int jb = blockIdx.x;
    const int xcd = jb & 7;
    const int tb = jb >> 3;                    // [0, NXG*NYG)
    const int mg = xcd >> 1, ng = xcd & 1;
    const int m0 = (mg * NYG + tb / NXG) * TM;
    const int n0 = (ng * NXG + tb % NXG) * TN;

    const int wave = tid >> 6, lane = tid & 63;
    const int wm = wave >> 1, wn = wave & 1;
    const int quad = lane >> 4, l16 = lane & 15;
    const int swz = l16 & (CPR - 1);

    f32x4 acc[MI][NJ] = {};

    auto stage = [&](int t, int b) {
        const size_t kk = (size_t)t * BK;
        #pragma unroll
        for (int it = 0; it < TM * BK / 2048; ++it) {
            int c = tid + 256 * it;
            int row = c / CPR, jj = c % CPR;
            int col8 = (jj ^ (row & (CPR - 1))) * 8;
            GLOAD_LDS(A + (size_t)(m0 + row) * K + kk + col8,
                      As + (size_t)b * TM * BK + (size_t)c * 8);
        }
        #pragma unroll
        for (int it = 0; it < TN * BK / 2048; ++it) {
            int c = tid + 256 * it;
            int row = c / CPR, jj = c % CPR;
            int col8 = (jj ^ (row & (CPR - 1))) * 8;
            GLOAD_LDS(BT + (size_t)(n0 + row) * K + kk + col8,
                      Bs + (size_t)b * TN * BK + (size_t)c * 8);
        }
    };

    stage(0, 0);
    for (int t = 0; t < NT; ++t) {
        const int cur = t & 1;
        if (t + 1 < NT) {
            stage(t + 1, cur ^ 1);
            // wait tile t's N_LD loads; leave tile t+1's in flight (never 0)
            if constexpr (N_LD == 8) asm volatile("s_waitcnt vmcnt(8)" ::: "memory");
            else                     asm volatile("s_waitcnt vmcnt(4)" ::: "memory");
        } else {
            asm volatile("s_waitcnt vmcnt(0)" ::: "memory");
        }
        __builtin_amdgcn_s_barrier();

        const unsigned short* Asb = As + (size_t)cur * TM * BK;
        const unsigned short* Bsb = Bs + (size_t)cur * TN * BK;
        #pragma unroll
        for (int kk2 = 0; kk2 < BK / 32; ++kk2) {
            bf16x8 af[MI], bfv[NJ];
            #pragma unroll
            for (int i = 0; i < MI; i++) {
                int row = 16 * MI * wm + 16 * i + l16;
                int sj = (4 * kk2 + quad) ^ swz;
                af[i] = *(const bf16x8*)&Asb[row * BK + sj * 8];
            }
            #pragma unroll
            for (int j = 0; j < NJ; j++) {
                int row = 16 * NJ * wn + 16 * j + l16;
                int sj = (4 * kk2 + quad) ^ swz;
                bfv[j] = *(const bf16x8*)&Bsb[row * BK + sj * 8];
            }
            #pragma unroll
            for (int i = 0; i < MI; i++)
                #pragma unroll
                for (int j = 0; j < NJ; j++)
                    acc[i][j] = __builtin_amdgcn_mfma_f32_16x16x32_bf16(af[i], bfv[j], acc[i][j], 0, 0, 0);
        }
        // all this wave's ds_reads complete (results consumed), then barrier so
        // next iter's stage into buf[cur] can't race other waves' reads.
        asm volatile("s_waitcnt lgkmcnt(0)" ::: "memory");
        __builtin_amdgcn_s_barrier();
    }

    #pragma unroll
    for (int i = 0; i < MI; i++) {
        #pragma unroll
        for (int j = 0; j < NJ; j++) {
            int nl = n0 + 16 * NJ * wn + 16 * j + l16;
            float bval = 0.0f;
            if (MODE != EP_QKV) bval = bias[nl];
            #pragma unroll
            for (int r = 0; r < 4; r++) {
                int ml = m0 + 16 * MI * wm + 16 * i + quad * 4 + r;
                float v = acc[i][j][r];
                if (MODE == EP_QKV) {
                    int which = nl >> 10, rem = nl & 1023;
                    int hh = rem >> 6, d = rem & 63;
                    int bb = ml >> 11, t2 = ml & 2047;
                    int bh = bb * HEADS + hh;
                    // q pre-scale = (1/8) * log2(e) so softmax is a bare v_exp_f32 (2^x)
                    if (which == 0)      q_buf[((size_t)bh * SEQ + t2) * HD + d] = f2bf(v * 0.18033688011112042f);
                    else if (which == 1) k_buf[((size_t)bh * SEQ + t2) * HD + d] = f2bf(v);
                    else                 v_buf[((size_t)bh * SEQ + t2) * HD + d] = f2bf(v);
                } else if (MODE == EP_PROJ) {
                    float* x1 = (float*)out0;
                    x1[(size_t)ml * DIMC + nl] = res[(size_t)ml * DIMC + nl] + v + bval;
                } else if (MODE == EP_FC1) {
                    float g = v + bval;
                    float u = 1.5957691216f * (g + 0.044715f * g * g * g);
                    float gv = g / (1.0f + __expf(-u));
                    ((unsigned short*)out0)[(size_t)ml * HIDDENC + nl] = f2bf(gv);
                } else {
                    ((float*)out0)[(size_t)ml * DIMC + nl] =
                        res[(size_t)ml * DIMC + nl] + v + bval;
                }
            }
        }
    }
}

// ---------------------------------------------------------------------------
// Split-K flash attention partials. No online max (|s|<~7 after LN).
// Key-padding semantics MUST match the reference's fp32 "+(-1e9)":
// all masked scores collapse to the SAME value (uniform softmax when a row's
// visible keys are all masked). So masked keys get a CONSTANT weight 1e-13:
// normal rows see <=1e-7 relative perturbation; all-masked rows get
// exactly-uniform weights, matching ref. Partials combine by plain summation.
//
// Swapped QK^T (S^T = mfma(K,Q)): lane holds one q (=l16) and 4 consecutive
// keys -> P-store = 2x cvt_pk + 1x ds_write_b64 per ct; PV A-read is a
// contiguous ds_read_b128 from the XOR-swizzled row-major Ps[q][key].
// O_part store staged through LDS -> 2x dwordx4/lane full-line writes.
// XCD-aware 1D swizzle keeps all 80 slots of one (b,h) on one XCD.
// ---------------------------------------------------------------------------
#define KP 72
#define PMASK 1e-13f
__global__ __launch_bounds__(256, 6) void attn_partial(
    const unsigned short* __restrict__ q_buf,
    const unsigned short* __restrict__ k_buf,
    const unsigned short* __restrict__ vT_buf,
    const int* __restrict__ mask,
    unsigned short* __restrict__ opart0,   // d_out scratch (bh 0..24)
    unsigned short* __restrict__ opart1,   // x1 scratch (bh 25..31)
    float* __restrict__ l_part) {
    __shared__ __align__(16) unsigned short Ks[64 * KP];
    __shared__ __align__(16) unsigned short Vs[64 * KP];
    __shared__ __align__(16) unsigned short Ps[4 * 16 * 64];  // per-wave swizzled P[q][key]; O-stage after loop
    __shared__ __align__(16) float Msf[64];

    // XCD-aware decode: consecutive blockIdx round-robin XCDs; keep all 80
    // slots of one bh on one XCD. Bijective on [0,2560).
    const int j = blockIdx.x;
    const int xcd = j & 7;
    const int t = j >> 3;            // 0..319
    const int slot = t % NSLOT;
    const int bg = t / NSLOT;        // 0..3
    const int bh = bg * 8 + xcd;     // 0..31
    const int bb = bh >> 4, h = bh & 15;

    // slot -> (qt, chunk)
    int s = slot, qt, c;
    if (s < 8)       { qt = s;              c = 0;     }
    else if (s < 24) { s -= 8;  qt = 8  + (s >> 1); c = s & 1; }
    else if (s < 48) { s -= 24; qt = 16 + s / 3;    c = s % 3; }
    else             { s -= 48; qt = 24 + (s >> 2); c = s & 3; }
    const int kt0 = c * 8;
    const int kt1 = min(kt0 + 8, qt + 1);

    const int tid = threadIdx.x, wave = tid >> 6, lane = tid & 63;
    const int quad = lane >> 4, l16 = lane & 15;
    const unsigned short* qp = q_buf + (size_t)bh * SEQ * HD;
    const unsigned short* kp = k_buf + (size_t)bh * SEQ * HD;
    const unsigned short* vp = vT_buf + (size_t)bh * HD * SEQ;
    const int* mrow_ptr = mask + bb * SEQ;

    const int qrow = qt * 64 + wave * 16 + l16;   // this lane's q (global)
    bf16x8 qf[2];
    qf[0] = *(const bf16x8*)(qp + (size_t)qrow * HD + 8 * quad);
    qf[1] = *(const bf16x8*)(qp + (size_t)qrow * HD + 32 + 8 * quad);

    f32x4 o[4] = {};
    float lsum = 0.0f;

    const int r0 = tid >> 3, c0 = (tid & 7) * 8;
    const int r1 = r0 + 32;

    // per-wave swizzled Ps addressing (bytes): row = q = l16, 128 B rows
    char* psb = (char*)Ps + wave * 2048 + l16 * 128;
    const int swz = (l16 & 7) << 4;

    // prefetch first tile of the chunk; Msf holds 1.0 = masked, 0.0 = visible
    uint4 pk0, pk1, pv0, pv1; float pmv = 0.0f;
    pk0 = *(const uint4*)(kp + (size_t)(kt0 * 64 + r0) * HD + c0);
    pk1 = *(const uint4*)(kp + (size_t)(kt0 * 64 + r1) * HD + c0);
    pv0 = *(const uint4*)(vp + (size_t)r0 * SEQ + kt0 * 64 + c0);
    pv1 = *(const uint4*)(vp + (size_t)r1 * SEQ + kt0 * 64 + c0);
    if (tid < 64) pmv = mrow_ptr[kt0 * 64 + tid] ? 1.0f : 0.0f;

    for (int kt = kt0; kt < kt1; kt++) {
        __syncthreads();
        *(uint4*)&Ks[r0 * KP + c0] = pk0;
        *(uint4*)&Ks[r1 * KP + c0] = pk1;
        *(uint4*)&Vs[r0 * KP + c0] = pv0;
        *(uint4*)&Vs[r1 * KP + c0] = pv1;
        if (tid < 64) Msf[tid] = pmv;
        if (kt + 1 < kt1) {
            pk0 = *(const uint4*)(kp + (size_t)((kt + 1) * 64 + r0) * HD + c0);
            pk1 = *(const uint4*)(kp + (size_t)((kt + 1) * 64 + r1) * HD + c0);
            pv0 = *(const uint4*)(vp + (size_t)r0 * SEQ + (kt + 1) * 64 + c0);
            pv1 = *(const uint4*)(vp + (size_t)r1 * SEQ + (kt + 1) * 64 + c0);
            if (tid < 64) pmv = mrow_ptr[(kt + 1) * 64 + tid] ? 1.0f : 0.0f;
        }
        __syncthreads();

        // S^T = K @ Q^T : sc[ct][r] = S[key=16ct+4quad+r][q=l16]
        f32x4 sc[4];
        __builtin_amdgcn_s_setprio(1);
        #pragma unroll
        for (int ct = 0; ct < 4; ct++) {
            f32x4 z = {};
            #pragma unroll
            for (int ss = 0; ss < 2; ss++) {
                bf16x8 kf = *(const bf16x8*)&Ks[(16 * ct + l16) * KP + 32 * ss + 8 * quad];
                z = __builtin_amdgcn_mfma_f32_16x16x32_bf16(kf, qf[ss], z, 0, 0, 0);
            }
            sc[ct] = z;
        }
        __builtin_amdgcn_s_setprio(0);

        const bool diag = (kt == qt);
        #pragma unroll
        for (int ct = 0; ct < 4; ct++) {
            float4 mq = *(const float4*)&Msf[16 * ct + 4 * quad];
            float mfs[4] = {mq.x, mq.y, mq.z, mq.w};
            const int kg0 = kt * 64 + 16 * ct + 4 * quad;
            float pv4[4];
            #pragma unroll
            for (int r = 0; r < 4; r++) {
                float p = (mfs[r] != 0.0f) ? PMASK : exp2_fast(sc[ct][r]);
                if (diag && (kg0 + r) > qrow) p = 0.0f;
                lsum += p;
                pv4[r] = p;
            }
            uint2 w;
            w.x = cvt_pk_bf16(pv4[0], pv4[1]);
            w.y = cvt_pk_bf16(pv4[2], pv4[3]);
            // P[q=l16][key=16ct+4quad .. +3]: logical byte quad*8+ct*32, swizzled
            *(uint2*)(psb + ((quad * 8 + ct * 32) ^ swz)) = w;
        }
        asm volatile("" ::: "memory");   // order punned LDS write -> read

        __builtin_amdgcn_s_setprio(1);
        #pragma unroll
        for (int ss = 0; ss < 2; ss++) {
            bf16x8 pf = *(const bf16x8*)(psb + ((ss * 64 + quad * 16) ^ swz));
            #pragma unroll
            for (int dt = 0; dt < 4; dt++) {
                bf16x8 vf = *(const bf16x8*)&Vs[(16 * dt + l16) * KP + 32 * ss + 8 * quad];
                o[dt] = __builtin_amdgcn_mfma_f32_16x16x32_bf16(pf, vf, o[dt], 0, 0, 0);
            }
        }
        __builtin_amdgcn_s_setprio(0);
    }

    // row-sum for q=l16 lives replicated across quads: butterfly over quads
    lsum += __shfl_xor(lsum, 16);
    lsum += __shfl_xor(lsum, 32);
    if (lane < 16)
        l_part[((size_t)bh * NSLOT + slot) * 64 + wave * 16 + lane] = lsum;

    // O store: stage the wave's 16x64 subtile in its private Ps region (dead
    // now), then write 2x dwordx4 per lane -> full-line coalesced HBM writes.
    unsigned short* Ls = Ps + wave * 1024;   // 16 rows x 64 cols bf16 = 2 KB
    #pragma unroll
    for (int dt = 0; dt < 4; dt++)
        #pragma unroll
        for (int r = 0; r < 4; r++)
            Ls[(quad * 4 + r) * 64 + 16 * dt + l16] = f2bf(o[dt][r]);
    asm volatile("" ::: "memory");           // order punned LDS write -> read
    unsigned short* ob = opart_base(opart0, opart1, bh)
                         + (size_t)slot * 4096 + wave * 1024;
    uint4 w0 = *(const uint4*)&Ls[lane * 8];
    uint4 w1 = *(const uint4*)&Ls[512 + lane * 8];
    *(uint4*)(ob + lane * 8) = w0;
    *(uint4*)(ob + 512 + lane * 8) = w1;
}

// ---------------------------------------------------------------------------
// Combine partials: attn_o[bh][t][d] = (sum_c O_c) / (sum_c l_c), bf16.
// One block per (qt, h, b).
// ---------------------------------------------------------------------------
__global__ __launch_bounds__(256) void attn_combine(
    const unsigned short* __restrict__ opart0,
    const unsigned short* __restrict__ opart1,
    const float* __restrict__ l_part,
    unsigned short* __restrict__ attn_o) {
    const int qt = blockIdx.x, h = blockIdx.y, bb = blockIdx.z;
    const int bh = bb * HEADS + h;
    const int g = qt >> 3;
    const int n = g + 1;
    const int baseB[4] = {0, 8, 24, 48};
    const int slot0 = baseB[g] + (qt - 8 * g) * n;
    const int tid = threadIdx.x;
    __shared__ float linv[64];
    if (tid < 64) {
        float acc = 0.0f;
        for (int cc = 0; cc < n; cc++)
            acc += l_part[((size_t)bh * NSLOT + slot0 + cc) * 64 + tid];
        linv[tid] = 1.0f / acc;
    }
    __syncthreads();
    const unsigned short* ob = opart_base((unsigned short*)opart0, (unsigned short*)opart1, bh)
                               + (size_t)slot0 * 4096;
    #pragma unroll
    for (int i = 0; i < 16; i++) {
        int idx = i * 256 + tid;          // 0..4095
        int row = idx >> 6, d = idx & 63;
        float acc = 0.0f;
        for (int cc = 0; cc < n; cc++)
            acc += bf2f(ob[(size_t)cc * 4096 + idx]);
        attn_o[((size_t)(bb * SEQ + qt * 64 + row)) * DIMC + h * HD + d] =
            f2bf(acc * linv[row]);
    }
}

// ---------------------------------------------------------------------------
extern "C" void kernel_launch(void* const* d_in, const int* in_sizes, int n_in,
                              void* d_out, int out_size, void* d_ws, size_t ws_size,
                              hipStream_t stream) {
    const float* x     = (const float*)d_in[0];
    const int*   mask  = (const int*)d_in[1];
    const float* ln1w  = (const float*)d_in[2];
    const float* ln1b  = (const float*)d_in[3];
    const float* qkvw  = (const float*)d_in[4];
    const float* projw = (const float*)d_in[5];
    const float* projb = (const float*)d_in[6];
    const float* ln2w  = (const float*)d_in[7];
    const float* ln2b  = (const float*)d_in[8];
    const float* fc1w  = (const float*)d_in[9];
    const float* fc1b  = (const float*)d_in[10];
    const float* fc2w  = (const float*)d_in[11];
    const float* fc2b  = (const float*)d_in[12];

    // Workspace (80 MB, lifetime reuse):
    //  [0,6M)    qkv_wT (dead after QKV gemm) | l_part [0,640K) during attn
    //  [6,8M)    proj_wT
    //  [8,16M)   fc1_wT
    //  [16,24M)  fc2_wT
    //  [24,32M)  ln_buf (ln1, later ln2)
    //  [32,40M)  q_buf   | h_buf [32,64M) at FC1
    //  [40,48M)  k_buf
    //  [48,56M)  v_buf -> attn_o (combine output)
    //  [56,64M)  vT_buf
    //  [64,80M)  O_part overflow (bh 25..31, 4.6M) during attn; x1 fp32 after
    // d_out (16.8M fp32 out): O_part scratch (bh 0..24) until FC2 overwrites.
    char* base = (char*)d_ws;
    unsigned short* qkv_wT  = (unsigned short*)(base);
    float*          l_part  = (float*)(base);                              // alias, post-QKV
    unsigned short* proj_wT = (unsigned short*)(base + (size_t)6  * 1024 * 1024);
    unsigned short* fc1_wT  = (unsigned short*)(base + (size_t)8  * 1024 * 1024);
    unsigned short* fc2_wT  = (unsigned short*)(base + (size_t)16 * 1024 * 1024);
    unsigned short* ln_buf  = (unsigned short*)(base + (size_t)24 * 1024 * 1024);
    unsigned short* q_buf   = (unsigned short*)(base + (size_t)32 * 1024 * 1024);
    unsigned short* k_buf   = (unsigned short*)(base + (size_t)40 * 1024 * 1024);
    unsigned short* v_buf   = (unsigned short*)(base + (size_t)48 * 1024 * 1024);
    unsigned short* attn_o  = (unsigned short*)(base + (size_t)48 * 1024 * 1024); // alias v_buf
    unsigned short* vT_buf  = (unsigned short*)(base + (size_t)56 * 1024 * 1024);
    unsigned short* h_buf   = (unsigned short*)(base + (size_t)32 * 1024 * 1024); // reuse
    float*          x1      = (float*)(base + (size_t)64 * 1024 * 1024);
    unsigned short* opart1  = (unsigned short*)(base + (size_t)64 * 1024 * 1024); // alias x1
    unsigned short* opart0  = (unsigned short*)d_out;                             // scratch until FC2

    // 1. all 4 weight transposes in one launch
    fused_transpose<<<3072, 256, 0, stream>>>(qkvw, projw, fc1w, fc2w,
                                              qkv_wT, proj_wT, fc1_wT, fc2_wT);

    // 2. LN1 (fp32 x -> bf16)
    ln_kernel<<<MTOK, 256, 0, stream>>>(x, ln1w, ln1b, ln_buf);

    // 3. QKV GEMM -> q (pre-scaled by log2e/8), k, v (all [bh][t][d])
    gemm_kernel<EP_QKV, 3072, 1024, 128, 128, 64><<<768, 256, 0, stream>>>(
        ln_buf, qkv_wT, nullptr, nullptr, nullptr, q_buf, k_buf, v_buf);

    // 4. V transpose -> vT [bh][d][t]
    transpose_v<<<dim3(SEQ / 64, BATCH * HEADS), 256, 0, stream>>>(v_buf, vT_buf);

    // 5a. split-K attention partials (2560 blocks, XCD-swizzled 1D grid)
    attn_partial<<<NSLOT * HEADS * BATCH, 256, 0, stream>>>(
        q_buf, k_buf, vT_buf, mask, opart0, opart1, l_part);

    // 5b. combine -> attn_o (aliases v_buf, dead now)
    attn_combine<<<dim3(SEQ / 64, HEADS, BATCH), 256, 0, stream>>>(
        opart0, opart1, l_part, attn_o);

    // 6. proj GEMM + residual(x fp32) -> x1 (fp32; O_part overflow dead now)
    gemm_kernel<EP_PROJ, 1024, 1024, 64, 64, 64><<<1024, 256, 0, stream>>>(
        attn_o, proj_wT, projb, x, x1, nullptr, nullptr, nullptr);

    // 7. LN2 (fp32 x1 -> bf16)
    ln_kernel<<<MTOK, 256, 0, stream>>>(x1, ln2w, ln2b, ln_buf);

    // 8. FC1 + GELU -> h_buf (bf16)
    gemm_kernel<EP_FC1, 4096, 1024, 128, 128, 64><<<1024, 256, 0, stream>>>(
        ln_buf, fc1_wT, fc1b, nullptr, h_buf, nullptr, nullptr, nullptr);

    // 9. FC2 + residual(x1) -> d_out (fp32; overwrites O_part scratch fully)
    gemm_kernel<EP_FC2, 1024, 4096, 64, 64, 64><<<1024, 256, 0, stream>>>(
        h_buf, fc2_wT, fc2b, x1, d_out, nullptr, nullptr, nullptr);
}

// Round 6
// 351.963 us; speedup vs baseline: 1.1455x; 1.0710x over previous
//
#include <hip/hip_runtime.h>
#include <stdint.h>

#define DIMC 1024
#define HEADS 16
#define HD 64
#define HIDDENC 4096
#define BATCH 2
#define SEQ 2048
#define MTOK (BATCH*SEQ)
#define NSLOT 80            // split-K chunk slots per (b,h): 8*1+8*2+8*3+8*4
#define BH_ELEMS (NSLOT*64*64)   // bf16 elems of O_part per bh = 327680

typedef __bf16 bf16x8 __attribute__((ext_vector_type(8)));
typedef float f32x4 __attribute__((ext_vector_type(4)));

__device__ __forceinline__ float bf2f(unsigned short u) {
    union { unsigned int u; float f; } v; v.u = ((unsigned int)u) << 16; return v.f;
}
__device__ __forceinline__ unsigned short f2bf(float f) {
    union { float f; unsigned int u; } v; v.f = f;
    unsigned int r = v.u + 0x7fffu + ((v.u >> 16) & 1u);
    return (unsigned short)(r >> 16);
}
// pack 2 f32 -> 2 bf16 (RNE), src0 -> low half (T12 recipe, guide-verified)
__device__ __forceinline__ unsigned int cvt_pk_bf16(float lo, float hi) {
    unsigned int r;
    asm("v_cvt_pk_bf16_f32 %0, %1, %2" : "=v"(r) : "v"(lo), "v"(hi));
    return r;
}
// 2^x (log2e is pre-folded into the Q scale)
__device__ __forceinline__ float exp2_fast(float x) {
#if __has_builtin(__builtin_amdgcn_exp2f)
    return __builtin_amdgcn_exp2f(x);
#else
    float r;
    asm("v_exp_f32 %0, %1" : "=v"(r) : "v"(x));
    return r;
#endif
}

#define GLOAD_LDS(g, l) \
    __builtin_amdgcn_global_load_lds( \
        (const __attribute__((address_space(1))) void*)(g), \
        (__attribute__((address_space(3))) void*)(l), 16, 0, 0)

// O_part is split across d_out (first 25 bh) and the x1 region (last 7 bh).
__device__ __forceinline__ unsigned short* opart_base(
    unsigned short* o0, unsigned short* o1, int bh) {
    return (bh < 25) ? (o0 + (size_t)bh * BH_ELEMS)
                     : (o1 + (size_t)(bh - 25) * BH_ELEMS);
}

// ---------------------------------------------------------------------------
// Fused weight transposes: fp32 (K x N) -> bf16 (N x K) for all 4 weights.
// ---------------------------------------------------------------------------
__device__ __forceinline__ void tp_tile(const float* __restrict__ in,
                                        unsigned short* __restrict__ out,
                                        int K, int N, int tn, int tk, int tid,
                                        unsigned short (*tile)[65]) {
    for (int c = tid; c < 1024; c += 256) {
        int r = c >> 4, coff = (c & 15) * 4;
        float4 v = *(const float4*)(in + (size_t)(tk + r) * N + tn + coff);
        tile[r][coff + 0] = f2bf(v.x);
        tile[r][coff + 1] = f2bf(v.y);
        tile[r][coff + 2] = f2bf(v.z);
        tile[r][coff + 3] = f2bf(v.w);
    }
    __syncthreads();
    for (int c = tid; c < 512; c += 256) {
        int rn = c >> 3, off = (c & 7) * 8;
        unsigned short tmp[8];
        #pragma unroll
        for (int j = 0; j < 8; j++) tmp[j] = tile[off + j][rn];
        *(uint4*)(out + (size_t)(tn + rn) * K + tk + off) = *(uint4*)tmp;
    }
}

__global__ __launch_bounds__(256) void fused_transpose(
    const float* __restrict__ qkvw, const float* __restrict__ projw,
    const float* __restrict__ fc1w, const float* __restrict__ fc2w,
    unsigned short* __restrict__ qkv_wT, unsigned short* __restrict__ proj_wT,
    unsigned short* __restrict__ fc1_wT, unsigned short* __restrict__ fc2_wT) {
    __shared__ unsigned short tile[64][65];
    int id = blockIdx.x, tid = threadIdx.x;
    if (id < 768) {
        tp_tile(qkvw, qkv_wT, 1024, 3072, (id % 48) * 64, (id / 48) * 64, tid, tile);
    } else if (id < 1024) {
        id -= 768;
        tp_tile(projw, proj_wT, 1024, 1024, (id % 16) * 64, (id / 16) * 64, tid, tile);
    } else if (id < 2048) {
        id -= 1024;
        tp_tile(fc1w, fc1_wT, 1024, 4096, (id % 64) * 64, (id / 64) * 64, tid, tile);
    } else {
        id -= 2048;
        tp_tile(fc2w, fc2_wT, 4096, 1024, (id % 16) * 64, (id / 16) * 64, tid, tile);
    }
}

// ---------------------------------------------------------------------------
// LayerNorm: f32 input, f32 w/b, bf16 output. One block per row (DIMC=1024).
// ---------------------------------------------------------------------------
__global__ __launch_bounds__(256) void ln_kernel(const float* __restrict__ inp,
                                                 const float* __restrict__ w,
                                                 const float* __restrict__ b,
                                                 unsigned short* __restrict__ out) {
    int row = blockIdx.x;
    int tid = threadIdx.x;
    int base = tid * 4;
    float4 v = *(const float4*)(inp + (size_t)row * DIMC + base);
    float x[4] = {v.x, v.y, v.z, v.w};
    float s1 = x[0] + x[1] + x[2] + x[3];
    float s2 = x[0]*x[0] + x[1]*x[1] + x[2]*x[2] + x[3]*x[3];
    #pragma unroll
    for (int off = 32; off > 0; off >>= 1) {
        s1 += __shfl_xor(s1, off);
        s2 += __shfl_xor(s2, off);
    }
    __shared__ float red[8];
    int wv = tid >> 6;
    if ((tid & 63) == 0) { red[wv] = s1; red[4 + wv] = s2; }
    __syncthreads();
    s1 = red[0] + red[1] + red[2] + red[3];
    s2 = red[4] + red[5] + red[6] + red[7];
    float mean = s1 * (1.0f / DIMC);
    float var  = s2 * (1.0f / DIMC) - mean * mean;
    float rstd = rsqrtf(var + 1e-5f);
    float4 wv4 = *(const float4*)(w + base);
    float4 bv4 = *(const float4*)(b + base);
    ushort4 o;
    o.x = f2bf((x[0] - mean) * rstd * wv4.x + bv4.x);
    o.y = f2bf((x[1] - mean) * rstd * wv4.y + bv4.y);
    o.z = f2bf((x[2] - mean) * rstd * wv4.z + bv4.z);
    o.w = f2bf((x[3] - mean) * rstd * wv4.w + bv4.w);
    *(ushort4*)(out + (size_t)row * DIMC + base) = o;
}

// ---------------------------------------------------------------------------
// bf16 MFMA GEMM: C(M x N) = A(M x K) @ BT(N x K)^T.
// Tile TM x TN, 4 waves (2x2), XOR-swizzled LDS, global_load_lds staging,
// double-buffered with counted vmcnt (R4).
//
// Round 6 mapping (A/B-measured):
//  - QKV/FC1 (TM=TN=128): 2D dim3 grid (R4 mapping). R5 rectangle REGRESSED
//    FC1 66->79 (co-resident blocks lockstep-read the same A-panel lines);
//    dim3 spreads co-resident blocks over different m-rows.
//  - PROJ/FC2 (TN=64): 1D XCD rectangle (MG=4 x NG=2). R4 evidence: naive
//    dim3 put each m-tile's n-blocks on all 8 XCDs -> A-dup=8, FETCH 143MB.
// ---------------------------------------------------------------------------
enum { EP_QKV = 0, EP_PROJ = 1, EP_FC1 = 2, EP_FC2 = 3 };

template <int MODE, int N, int K, int TM, int TN, int BK>
__global__ __launch_bounds__(256) void gemm_kernel(
    const unsigned short* __restrict__ A,
    const unsigned short* __restrict__ BT,
    const float* __restrict__ bias,
    const float* __restrict__ res,      // fp32 residual (PROJ: x, FC2: x1)
    void* __restrict__ out0,
    unsigned short* __restrict__ q_buf,
    unsigned short* __restrict__ k_buf,
    unsigned short* __restrict__ v_buf) {  // QKV: vT_buf [bh][d][t]
    constexpr int MI = TM / 32;          // m-fragments per wave (2 waves in m)
    constexpr int NJ = TN / 32;          // n-fragments per wave (2 waves in n)
    constexpr int CPR = BK / 8;
    constexpr int NT = K / BK;
    constexpr int N_LD = (TM + TN) * BK / 2048;  // gload_lds per thread per tile
    static_assert(N_LD == 8 || N_LD == 4, "vmcnt literal");
    constexpr int NX = N / TN;
    constexpr int NY = MTOK / TM;
    constexpr int MG = 4, NG = 2;        // XCD rectangle partition (PROJ/FC2)
    constexpr int NXG = NX / NG, NYG = NY / MG;

    __shared__ __align__(16) unsigned short As[2 * TM * BK];
    __shared__ __align__(16) unsigned short Bs[2 * TN * BK];
    const int tid = threadIdx.x;

    int m0, n0;
    if constexpr (MODE == EP_PROJ || MODE == EP_FC2) {
        // 1D grid, consecutive ids round-robin XCDs -> rectangle per XCD
        const int jb = blockIdx.x;
        const int xcd = jb & 7;
        const int tb = jb >> 3;
        const int mg = xcd >> 1, ng = xcd & 1;
        m0 = (mg * NYG + tb / NXG) * TM;
        n0 = (ng * NXG + tb % NXG) * TN;
    } else {
        m0 = blockIdx.y * TM;
        n0 = blockIdx.x * TN;
    }

    const int wave = tid >> 6, lane = tid & 63;
    const int wm = wave >> 1, wn = wave & 1;
    const int quad = lane >> 4, l16 = lane & 15;
    const int swz = l16 & (CPR - 1);

    f32x4 acc[MI][NJ] = {};

    auto stage = [&](int t, int b) {
        const size_t kk = (size_t)t * BK;
        #pragma unroll
        for (int it = 0; it < TM * BK / 2048; ++it) {
            int c = tid + 256 * it;
            int row = c / CPR, jj = c % CPR;
            int col8 = (jj ^ (row & (CPR - 1))) * 8;
            GLOAD_LDS(A + (size_t)(m0 + row) * K + kk + col8,
                      As + (size_t)b * TM * BK + (size_t)c * 8);
        }
        #pragma unroll
        for (int it = 0; it < TN * BK / 2048; ++it) {
            int c = tid + 256 * it;
            int row = c / CPR, jj = c % CPR;
            int col8 = (jj ^ (row & (CPR - 1))) * 8;
            GLOAD_LDS(BT + (size_t)(n0 + row) * K + kk + col8,
                      Bs + (size_t)b * TN * BK + (size_t)c * 8);
        }
    };

    stage(0, 0);
    for (int t = 0; t < NT; ++t) {
        const int cur = t & 1;
        if (t + 1 < NT) {
            stage(t + 1, cur ^ 1);
            // wait tile t's N_LD loads; leave tile t+1's in flight (never 0)
            if constexpr (N_LD == 8) asm volatile("s_waitcnt vmcnt(8)" ::: "memory");
            else                     asm volatile("s_waitcnt vmcnt(4)" ::: "memory");
        } else {
            asm volatile("s_waitcnt vmcnt(0)" ::: "memory");
        }
        __builtin_amdgcn_s_barrier();

        const unsigned short* Asb = As + (size_t)cur * TM * BK;
        const unsigned short* Bsb = Bs + (size_t)cur * TN * BK;
        #pragma unroll
        for (int kk2 = 0; kk2 < BK / 32; ++kk2) {
            bf16x8 af[MI], bfv[NJ];
            #pragma unroll
            for (int i = 0; i < MI; i++) {
                int row = 16 * MI * wm + 16 * i + l16;
                int sj = (4 * kk2 + quad) ^ swz;
                af[i] = *(const bf16x8*)&Asb[row * BK + sj * 8];
            }
            #pragma unroll
            for (int j = 0; j < NJ; j++) {
                int row = 16 * NJ * wn + 16 * j + l16;
                int sj = (4 * kk2 + quad) ^ swz;
                bfv[j] = *(const bf16x8*)&Bsb[row * BK + sj * 8];
            }
            #pragma unroll
            for (int i = 0; i < MI; i++)
                #pragma unroll
                for (int j = 0; j < NJ; j++)
                    acc[i][j] = __builtin_amdgcn_mfma_f32_16x16x32_bf16(af[i], bfv[j], acc[i][j], 0, 0, 0);
        }
        // all this wave's ds_reads complete (results consumed), then barrier so
        // next iter's stage into buf[cur] can't race other waves' reads.
        asm volatile("s_waitcnt lgkmcnt(0)" ::: "memory");
        __builtin_amdgcn_s_barrier();
    }

    #pragma unroll
    for (int i = 0; i < MI; i++) {
        #pragma unroll
        for (int j = 0; j < NJ; j++) {
            int nl = n0 + 16 * NJ * wn + 16 * j + l16;
            if (MODE == EP_QKV) {
                int which = nl >> 10, rem = nl & 1023;
                int hh = rem >> 6, d = rem & 63;
                int ml0 = m0 + 16 * MI * wm + 16 * i + quad * 4;  // r=0..3 -> t0..t0+3
                int bb2 = ml0 >> 11, t0 = ml0 & 2047;
                int bh = bb2 * HEADS + hh;
                if (which == 2) {
                    // V written TRANSPOSED [bh][d][t]: 4 consecutive t -> one 8B store
                    uint2 w;
                    w.x = cvt_pk_bf16(acc[i][j][0], acc[i][j][1]);
                    w.y = cvt_pk_bf16(acc[i][j][2], acc[i][j][3]);
                    *(uint2*)(v_buf + ((size_t)bh * HD + d) * SEQ + t0) = w;
                } else if (which == 0) {
                    // q pre-scale = (1/8)*log2(e) so softmax is a bare v_exp_f32 (2^x)
                    #pragma unroll
                    for (int r = 0; r < 4; r++)
                        q_buf[((size_t)bh * SEQ + t0 + r) * HD + d] =
                            f2bf(acc[i][j][r] * 0.18033688011112042f);
                } else {
                    #pragma unroll
                    for (int r = 0; r < 4; r++)
                        k_buf[((size_t)bh * SEQ + t0 + r) * HD + d] = f2bf(acc[i][j][r]);
                }
            } else {
                float bval = bias[nl];
                #pragma unroll
                for (int r = 0; r < 4; r++) {
                    int ml = m0 + 16 * MI * wm + 16 * i + quad * 4 + r;
                    float v = acc[i][j][r];
                    if (MODE == EP_PROJ) {
                        float* x1 = (float*)out0;
                        x1[(size_t)ml * DIMC + nl] = res[(size_t)ml * DIMC + nl] + v + bval;
                    } else if (MODE == EP_FC1) {
                        float g = v + bval;
                        float u = 1.5957691216f * (g + 0.044715f * g * g * g);
                        float gv = g / (1.0f + __expf(-u));
                        ((unsigned short*)out0)[(size_t)ml * HIDDENC + nl] = f2bf(gv);
                    } else {
                        ((float*)out0)[(size_t)ml * DIMC + nl] =
                            res[(size_t)ml * DIMC + nl] + v + bval;
                    }
                }
            }
        }
    }
}

// ---------------------------------------------------------------------------
// Split-K flash attention partials. No online max (|s|<~7 after LN).
// Key-padding semantics MUST match the reference's fp32 "+(-1e9)":
// all masked scores collapse to the SAME value (uniform softmax when a row's
// visible keys are all masked). So masked keys get a CONSTANT weight 1e-13:
// normal rows see <=1e-7 relative perturbation; all-masked rows get
// exactly-uniform weights, matching ref. Partials combine by plain summation.
//
// Swapped QK^T (S^T = mfma(K,Q)): lane holds one q (=l16) and 4 consecutive
// keys -> P-store = 2x cvt_pk + 1x ds_write_b64 per ct; PV A-read is a
// contiguous ds_read_b128 from the XOR-swizzled row-major Ps[q][key].
// O_part store staged through LDS -> 2x dwordx4/lane full-line writes.
// XCD-aware 1D swizzle keeps all 80 slots of one (b,h) on one XCD.
// ---------------------------------------------------------------------------
#define KP 72
#define PMASK 1e-13f
__global__ __launch_bounds__(256, 6) void attn_partial(
    const unsigned short* __restrict__ q_buf,
    const unsigned short* __restrict__ k_buf,
    const unsigned short* __restrict__ vT_buf,
    const int* __restrict__ mask,
    unsigned short* __restrict__ opart0,   // d_out scratch (bh 0..24)
    unsigned short* __restrict__ opart1,   // x1 scratch (bh 25..31)
    float* __restrict__ l_part) {
    __shared__ __align__(16) unsigned short Ks[64 * KP];
    __shared__ __align__(16) unsigned short Vs[64 * KP];
    __shared__ __align__(16) unsigned short Ps[4 * 16 * 64];  // per-wave swizzled P[q][key]; O-stage after loop
    __shared__ __align__(16) float Msf[64];

    // XCD-aware decode: consecutive blockIdx round-robin XCDs; keep all 80
    // slots of one bh on one XCD. Bijective on [0,2560).
    const int j = blockIdx.x;
    const int xcd = j & 7;
    const int t = j >> 3;            // 0..319
    const int slot = t % NSLOT;
    const int bg = t / NSLOT;        // 0..3
    const int bh = bg * 8 + xcd;     // 0..31
    const int bb = bh >> 4, h = bh & 15;

    // slot -> (qt, chunk)
    int s = slot, qt, c;
    if (s < 8)       { qt = s;              c = 0;     }
    else if (s < 24) { s -= 8;  qt = 8  + (s >> 1); c = s & 1; }
    else if (s < 48) { s -= 24; qt = 16 + s / 3;    c = s % 3; }
    else             { s -= 48; qt = 24 + (s >> 2); c = s & 3; }
    const int kt0 = c * 8;
    const int kt1 = min(kt0 + 8, qt + 1);

    const int tid = threadIdx.x, wave = tid >> 6, lane = tid & 63;
    const int quad = lane >> 4, l16 = lane & 15;
    const unsigned short* qp = q_buf + (size_t)bh * SEQ * HD;
    const unsigned short* kp = k_buf + (size_t)bh * SEQ * HD;
    const unsigned short* vp = vT_buf + (size_t)bh * HD * SEQ;
    const int* mrow_ptr = mask + bb * SEQ;

    const int qrow = qt * 64 + wave * 16 + l16;   // this lane's q (global)
    bf16x8 qf[2];
    qf[0] = *(const bf16x8*)(qp + (size_t)qrow * HD + 8 * quad);
    qf[1] = *(const bf16x8*)(qp + (size_t)qrow * HD + 32 + 8 * quad);

    f32x4 o[4] = {};
    float lsum = 0.0f;

    const int r0 = tid >> 3, c0 = (tid & 7) * 8;
    const int r1 = r0 + 32;

    // per-wave swizzled Ps addressing (bytes): row = q = l16, 128 B rows
    char* psb = (char*)Ps + wave * 2048 + l16 * 128;
    const int swz = (l16 & 7) << 4;

    // prefetch first tile of the chunk; Msf holds 1.0 = masked, 0.0 = visible
    uint4 pk0, pk1, pv0, pv1; float pmv = 0.0f;
    pk0 = *(const uint4*)(kp + (size_t)(kt0 * 64 + r0) * HD + c0);
    pk1 = *(const uint4*)(kp + (size_t)(kt0 * 64 + r1) * HD + c0);
    pv0 = *(const uint4*)(vp + (size_t)r0 * SEQ + kt0 * 64 + c0);
    pv1 = *(const uint4*)(vp + (size_t)r1 * SEQ + kt0 * 64 + c0);
    if (tid < 64) pmv = mrow_ptr[kt0 * 64 + tid] ? 1.0f : 0.0f;

    for (int kt = kt0; kt < kt1; kt++) {
        __syncthreads();
        *(uint4*)&Ks[r0 * KP + c0] = pk0;
        *(uint4*)&Ks[r1 * KP + c0] = pk1;
        *(uint4*)&Vs[r0 * KP + c0] = pv0;
        *(uint4*)&Vs[r1 * KP + c0] = pv1;
        if (tid < 64) Msf[tid] = pmv;
        if (kt + 1 < kt1) {
            pk0 = *(const uint4*)(kp + (size_t)((kt + 1) * 64 + r0) * HD + c0);
            pk1 = *(const uint4*)(kp + (size_t)((kt + 1) * 64 + r1) * HD + c0);
            pv0 = *(const uint4*)(vp + (size_t)r0 * SEQ + (kt + 1) * 64 + c0);
            pv1 = *(const uint4*)(vp + (size_t)r1 * SEQ + (kt + 1) * 64 + c0);
            if (tid < 64) pmv = mrow_ptr[(kt + 1) * 64 + tid] ? 1.0f : 0.0f;
        }
        __syncthreads();

        // S^T = K @ Q^T : sc[ct][r] = S[key=16ct+4quad+r][q=l16]
        f32x4 sc[4];
        __builtin_amdgcn_s_setprio(1);
        #pragma unroll
        for (int ct = 0; ct < 4; ct++) {
            f32x4 z = {};
            #pragma unroll
            for (int ss = 0; ss < 2; ss++) {
                bf16x8 kf = *(const bf16x8*)&Ks[(16 * ct + l16) * KP + 32 * ss + 8 * quad];
                z = __builtin_amdgcn_mfma_f32_16x16x32_bf16(kf, qf[ss], z, 0, 0, 0);
            }
            sc[ct] = z;
        }
        __builtin_amdgcn_s_setprio(0);

        const bool diag = (kt == qt);
        #pragma unroll
        for (int ct = 0; ct < 4; ct++) {
            float4 mq = *(const float4*)&Msf[16 * ct + 4 * quad];
            float mfs[4] = {mq.x, mq.y, mq.z, mq.w};
            const int kg0 = kt * 64 + 16 * ct + 4 * quad;
            float pv4[4];
            #pragma unroll
            for (int r = 0; r < 4; r++) {
                float p = (mfs[r] != 0.0f) ? PMASK : exp2_fast(sc[ct][r]);
                if (diag && (kg0 + r) > qrow) p = 0.0f;
                lsum += p;
                pv4[r] = p;
            }
            uint2 w;
            w.x = cvt_pk_bf16(pv4[0], pv4[1]);
            w.y = cvt_pk_bf16(pv4[2], pv4[3]);
            // P[q=l16][key=16ct+4quad .. +3]: logical byte quad*8+ct*32, swizzled
            *(uint2*)(psb + ((quad * 8 + ct * 32) ^ swz)) = w;
        }
        asm volatile("" ::: "memory");   // order punned LDS write -> read

        __builtin_amdgcn_s_setprio(1);
        #pragma unroll
        for (int ss = 0; ss < 2; ss++) {
            bf16x8 pf = *(const bf16x8*)(psb + ((ss * 64 + quad * 16) ^ swz));
            #pragma unroll
            for (int dt = 0; dt < 4; dt++) {
                bf16x8 vf = *(const bf16x8*)&Vs[(16 * dt + l16) * KP + 32 * ss + 8 * quad];
                o[dt] = __builtin_amdgcn_mfma_f32_16x16x32_bf16(pf, vf, o[dt], 0, 0, 0);
            }
        }
        __builtin_amdgcn_s_setprio(0);
    }

    // row-sum for q=l16 lives replicated across quads: butterfly over quads
    lsum += __shfl_xor(lsum, 16);
    lsum += __shfl_xor(lsum, 32);
    if (lane < 16)
        l_part[((size_t)bh * NSLOT + slot) * 64 + wave * 16 + lane] = lsum;

    // O store: stage the wave's 16x64 subtile in its private Ps region (dead
    // now), then write 2x dwordx4 per lane -> full-line coalesced HBM writes.
    unsigned short* Ls = Ps + wave * 1024;   // 16 rows x 64 cols bf16 = 2 KB
    #pragma unroll
    for (int dt = 0; dt < 4; dt++)
        #pragma unroll
        for (int r = 0; r < 4; r++)
            Ls[(quad * 4 + r) * 64 + 16 * dt + l16] = f2bf(o[dt][r]);
    asm volatile("" ::: "memory");           // order punned LDS write -> read
    unsigned short* ob = opart_base(opart0, opart1, bh)
                         + (size_t)slot * 4096 + wave * 1024;
    uint4 w0 = *(const uint4*)&Ls[lane * 8];
    uint4 w1 = *(const uint4*)&Ls[512 + lane * 8];
    *(uint4*)(ob + lane * 8) = w0;
    *(uint4*)(ob + 512 + lane * 8) = w1;
}

// ---------------------------------------------------------------------------
// Combine partials: attn_o[bh][t][d] = (sum_c O_c) / (sum_c l_c), bf16.
// One block per (qt, h, b). Vectorized: uint4 loads (8 bf16/lane).
// ---------------------------------------------------------------------------
__global__ __launch_bounds__(256) void attn_combine(
    const unsigned short* __restrict__ opart0,
    const unsigned short* __restrict__ opart1,
    const float* __restrict__ l_part,
    unsigned short* __restrict__ attn_o) {
    const int qt = blockIdx.x, h = blockIdx.y, bb = blockIdx.z;
    const int bh = bb * HEADS + h;
    const int g = qt >> 3;
    const int n = g + 1;
    const int baseB[4] = {0, 8, 24, 48};
    const int slot0 = baseB[g] + (qt - 8 * g) * n;
    const int tid = threadIdx.x;
    __shared__ float linv[64];
    if (tid < 64) {
        float acc = 0.0f;
        for (int cc = 0; cc < n; cc++)
            acc += l_part[((size_t)bh * NSLOT + slot0 + cc) * 64 + tid];
        linv[tid] = 1.0f / acc;
    }
    __syncthreads();
    const unsigned short* ob = opart_base((unsigned short*)opart0, (unsigned short*)opart1, bh)
                               + (size_t)slot0 * 4096;
    #pragma unroll
    for (int it = 0; it < 2; it++) {
        int base = (it * 256 + tid) * 8;     // 0..4088, 8-elem chunks
        int row = base >> 6, d = base & 63;
        float acc8[8] = {};
        for (int cc = 0; cc < n; cc++) {
            uint4 v = *(const uint4*)(ob + (size_t)cc * 4096 + base);
            const unsigned short* pv = (const unsigned short*)&v;
            #pragma unroll
            for (int e = 0; e < 8; e++) acc8[e] += bf2f(pv[e]);
        }
        float sc = linv[row];
        unsigned short tmp[8];
        #pragma unroll
        for (int e = 0; e < 8; e++) tmp[e] = f2bf(acc8[e] * sc);
        *(uint4*)(attn_o + ((size_t)(bb * SEQ + qt * 64 + row)) * DIMC + h * HD + d) =
            *(uint4*)tmp;
    }
}

// ---------------------------------------------------------------------------
extern "C" void kernel_launch(void* const* d_in, const int* in_sizes, int n_in,
                              void* d_out, int out_size, void* d_ws, size_t ws_size,
                              hipStream_t stream) {
    const float* x     = (const float*)d_in[0];
    const int*   mask  = (const int*)d_in[1];
    const float* ln1w  = (const float*)d_in[2];
    const float* ln1b  = (const float*)d_in[3];
    const float* qkvw  = (const float*)d_in[4];
    const float* projw = (const float*)d_in[5];
    const float* projb = (const float*)d_in[6];
    const float* ln2w  = (const float*)d_in[7];
    const float* ln2b  = (const float*)d_in[8];
    const float* fc1w  = (const float*)d_in[9];
    const float* fc1b  = (const float*)d_in[10];
    const float* fc2w  = (const float*)d_in[11];
    const float* fc2b  = (const float*)d_in[12];

    // Workspace (80 MB, lifetime reuse):
    //  [0,6M)    qkv_wT (dead after QKV gemm) | l_part [0,640K) during attn
    //  [6,8M)    proj_wT
    //  [8,16M)   fc1_wT
    //  [16,24M)  fc2_wT
    //  [24,32M)  ln_buf (ln1, later ln2)
    //  [32,40M)  q_buf   | h_buf [32,64M) at FC1
    //  [40,48M)  k_buf
    //  [48,56M)  attn_o (combine output)
    //  [56,64M)  vT_buf (written directly by QKV, transposed)
    //  [64,80M)  O_part overflow (bh 25..31, 4.6M) during attn; x1 fp32 after
    // d_out (16.8M fp32 out): O_part scratch (bh 0..24) until FC2 overwrites.
    char* base = (char*)d_ws;
    unsigned short* qkv_wT  = (unsigned short*)(base);
    float*          l_part  = (float*)(base);                              // alias, post-QKV
    unsigned short* proj_wT = (unsigned short*)(base + (size_t)6  * 1024 * 1024);
    unsigned short* fc1_wT  = (unsigned short*)(base + (size_t)8  * 1024 * 1024);
    unsigned short* fc2_wT  = (unsigned short*)(base + (size_t)16 * 1024 * 1024);
    unsigned short* ln_buf  = (unsigned short*)(base + (size_t)24 * 1024 * 1024);
    unsigned short* q_buf   = (unsigned short*)(base + (size_t)32 * 1024 * 1024);
    unsigned short* k_buf   = (unsigned short*)(base + (size_t)40 * 1024 * 1024);
    unsigned short* attn_o  = (unsigned short*)(base + (size_t)48 * 1024 * 1024);
    unsigned short* vT_buf  = (unsigned short*)(base + (size_t)56 * 1024 * 1024);
    unsigned short* h_buf   = (unsigned short*)(base + (size_t)32 * 1024 * 1024); // reuse
    float*          x1      = (float*)(base + (size_t)64 * 1024 * 1024);
    unsigned short* opart1  = (unsigned short*)(base + (size_t)64 * 1024 * 1024); // alias x1
    unsigned short* opart0  = (unsigned short*)d_out;                             // scratch until FC2

    // 1. all 4 weight transposes in one launch
    fused_transpose<<<3072, 256, 0, stream>>>(qkvw, projw, fc1w, fc2w,
                                              qkv_wT, proj_wT, fc1_wT, fc2_wT);

    // 2. LN1 (fp32 x -> bf16)
    ln_kernel<<<MTOK, 256, 0, stream>>>(x, ln1w, ln1b, ln_buf);

    // 3. QKV GEMM -> q (pre-scaled by log2e/8), k [bh][t][d]; V DIRECTLY
    //    transposed into vT_buf [bh][d][t] (packed 8B stores).
    gemm_kernel<EP_QKV, 3072, 1024, 128, 128, 64><<<dim3(24, 32), 256, 0, stream>>>(
        ln_buf, qkv_wT, nullptr, nullptr, nullptr, q_buf, k_buf, vT_buf);

    // 4. split-K attention partials (2560 blocks, XCD-swizzled 1D grid)
    attn_partial<<<NSLOT * HEADS * BATCH, 256, 0, stream>>>(
        q_buf, k_buf, vT_buf, mask, opart0, opart1, l_part);

    // 5. combine -> attn_o
    attn_combine<<<dim3(SEQ / 64, HEADS, BATCH), 256, 0, stream>>>(
        opart0, opart1, l_part, attn_o);

    // 6. proj GEMM + residual(x fp32) -> x1 (fp32; O_part overflow dead now)
    gemm_kernel<EP_PROJ, 1024, 1024, 64, 64, 64><<<1024, 256, 0, stream>>>(
        attn_o, proj_wT, projb, x, x1, nullptr, nullptr, nullptr);

    // 7. LN2 (fp32 x1 -> bf16)
    ln_kernel<<<MTOK, 256, 0, stream>>>(x1, ln2w, ln2b, ln_buf);

    // 8. FC1 + GELU -> h_buf (bf16)
    gemm_kernel<EP_FC1, 4096, 1024, 128, 128, 64><<<dim3(32, 32), 256, 0, stream>>>(
        ln_buf, fc1_wT, fc1b, nullptr, h_buf, nullptr, nullptr, nullptr);

    // 9. FC2 + residual(x1) -> d_out (fp32; overwrites O_part scratch fully)
    gemm_kernel<EP_FC2, 1024, 4096, 64, 64, 64><<<1024, 256, 0, stream>>>(
        h_buf, fc2_wT, fc2b, x1, d_out, nullptr, nullptr, nullptr);
}